// Round 8
// baseline (312.556 us; speedup 1.0000x reference)
//
#include <hip/hip_runtime.h>

typedef unsigned short u16;
typedef unsigned int u32;
typedef __bf16 bf16_t;
typedef bf16_t bf16x8 __attribute__((ext_vector_type(8)));
typedef float f32x2 __attribute__((ext_vector_type(2)));
typedef float f32x4 __attribute__((ext_vector_type(4)));
typedef float f32x16 __attribute__((ext_vector_type(16)));

#define DM 768
#define HD 64
#define NH 12
#define NB 2
#define SEQ 4096
#define MR (NB * SEQ)  // 8192

#define SCL2E_F (0.125f * 1.44269504088896340736f)  // 1/sqrt(64) * log2(e)

__device__ __forceinline__ u16 f2bf(float f) {
  union { float f; u32 u; } v;
  v.f = f;
  u32 r = v.u + 0x7FFFu + ((v.u >> 16) & 1u);  // RNE, finite inputs only
  return (u16)(r >> 16);
}

// hardware pack: lo16 = bf16(a), hi16 = bf16(b)
__device__ __forceinline__ u32 cvtpk(float a, float b) {
  u32 r;
  asm("v_cvt_pk_bf16_f32 %0, %1, %2" : "=v"(r) : "v"(a), "v"(b));
  return r;
}

// half-swap between two DISTINCT registers (never call with identical values):
// a_new = lanes<32 ? a : b[lane-32];  b_new = lanes<32 ? a[lane+32] : b
__device__ __forceinline__ void pl32swap(u32& a, u32& b) {
  asm volatile("v_permlane32_swap_b32 %0, %1" : "+v"(a), "+v"(b));
}

__device__ __forceinline__ f32x2 pkadd(f32x2 a, f32x2 b) {
  f32x2 r;
  asm("v_pk_add_f32 %0, %1, %2" : "=v"(r) : "v"(a), "v"(b));
  return r;
}

__device__ __forceinline__ bf16x8 ldb8(const u16* p) {
  return *reinterpret_cast<const bf16x8*>(p);
}

__device__ __forceinline__ f32x4 mfma16(bf16x8 a, bf16x8 b, f32x4 c) {
  return __builtin_amdgcn_mfma_f32_16x16x32_bf16(a, b, c, 0, 0, 0);
}

__device__ __forceinline__ f32x16 mfma32(bf16x8 a, bf16x8 b, f32x16 c) {
  return __builtin_amdgcn_mfma_f32_32x32x16_bf16(a, b, c, 0, 0, 0);
}

#define GLDS16(g, l)                                              \
  __builtin_amdgcn_global_load_lds(                               \
      (const __attribute__((address_space(1))) void*)(g),         \
      (__attribute__((address_space(3))) void*)(l), 16, 0, 0)

// ---------------------------------------------------------------- converts
__global__ __launch_bounds__(256) void cvt_kernel(const float* __restrict__ src,
                                                  u16* __restrict__ dst, int n8) {
  int i = blockIdx.x * 256 + threadIdx.x;
  if (i >= n8) return;
  const float4* s = reinterpret_cast<const float4*>(src) + (size_t)i * 2;
  float4 a = s[0], b = s[1];
  union { u16 u[8]; uint4 v; } o;
  o.u[0] = f2bf(a.x); o.u[1] = f2bf(a.y); o.u[2] = f2bf(a.z); o.u[3] = f2bf(a.w);
  o.u[4] = f2bf(b.x); o.u[5] = f2bf(b.y); o.u[6] = f2bf(b.z); o.u[7] = f2bf(b.w);
  reinterpret_cast<uint4*>(dst)[i] = o.v;
}

__global__ __launch_bounds__(256) void cvt_w_kernel(const float* __restrict__ w0,
                                                    const float* __restrict__ w1,
                                                    const float* __restrict__ w2,
                                                    const float* __restrict__ w3,
                                                    u16* __restrict__ dst) {
  const float* src = (blockIdx.y == 0) ? w0 : (blockIdx.y == 1) ? w1
                   : (blockIdx.y == 2) ? w2 : w3;
  u16* d = dst + (size_t)blockIdx.y * DM * DM;
  int i = blockIdx.x * 256 + threadIdx.x;
  const float4* s = reinterpret_cast<const float4*>(src) + (size_t)i * 2;
  float4 a = s[0], b = s[1];
  union { u16 u[8]; uint4 v; } o;
  o.u[0] = f2bf(a.x); o.u[1] = f2bf(a.y); o.u[2] = f2bf(a.z); o.u[3] = f2bf(a.w);
  o.u[4] = f2bf(b.x); o.u[5] = f2bf(b.y); o.u[6] = f2bf(b.z); o.u[7] = f2bf(b.w);
  reinterpret_cast<uint4*>(d)[i] = o.v;
}

// ---------------------------------------------------------------- QKV GEMM
// C[m,n] = sum_k A[m,k] * W[n,k] + bias[n]
// z==0 (Q): scaled by SCL2E, layout [bh][s][64]
// z==1 (K): layout [bh][s][64]
// z==2 (V): TRANSPOSED layout [bh][d][s]  (V^T, packed uint2 stores)
__global__ __launch_bounds__(256) void gemm_qkv_kernel(
    const u16* __restrict__ A, const u16* __restrict__ Wall,
    const float* __restrict__ b0, const float* __restrict__ b1,
    const float* __restrict__ b2, u16* __restrict__ O) {
  __shared__ __align__(16) u16 As[128 * 32];
  __shared__ __align__(16) u16 Bs[128 * 32];

  const int tid = threadIdx.x;
  const int w = tid >> 6, lane = tid & 63;
  const int l16 = lane & 15, lg = lane >> 4;
  const int wm = w >> 1, wn = w & 1;

  const int m0 = blockIdx.x * 128;
  const int n0 = blockIdx.y * 128;
  const int z = blockIdx.z;

  const u16* W = Wall + (size_t)z * DM * DM;
  const float* bias = (z == 0) ? b0 : ((z == 1) ? b1 : b2);
  u16* oz = O + (size_t)z * MR * DM;
  const float qscale = (z == 0) ? SCL2E_F : 1.f;

  f32x4 acc[4][4];
#pragma unroll
  for (int i = 0; i < 4; ++i)
#pragma unroll
    for (int j = 0; j < 4; ++j) {
      acc[i][j][0] = 0.f; acc[i][j][1] = 0.f;
      acc[i][j][2] = 0.f; acc[i][j][3] = 0.f;
    }

  for (int k0 = 0; k0 < DM; k0 += 32) {
#pragma unroll
    for (int i = 0; i < 2; ++i) {
      const int c = (w * 2 + i) * 64 + lane;
      const int m = c >> 2, kc = c & 3;
      GLDS16(A + (size_t)(m0 + m) * DM + (k0 + kc * 8),
             As + (size_t)(w * 2 + i) * 512);
      GLDS16(W + (size_t)(n0 + m) * DM + (k0 + kc * 8),
             Bs + (size_t)(w * 2 + i) * 512);
    }
    __syncthreads();
    bf16x8 af[4], bfv[4];
#pragma unroll
    for (int i = 0; i < 4; ++i)
      af[i] = ldb8(As + (wm * 64 + i * 16 + l16) * 32 + lg * 8);
#pragma unroll
    for (int j = 0; j < 4; ++j)
      bfv[j] = ldb8(Bs + (wn * 64 + j * 16 + l16) * 32 + lg * 8);
#pragma unroll
    for (int i = 0; i < 4; ++i)
#pragma unroll
      for (int j = 0; j < 4; ++j)
        acc[i][j] = mfma16(af[i], bfv[j], acc[i][j]);
    __syncthreads();
  }

#pragma unroll
  for (int i = 0; i < 4; ++i) {
    const int gm = m0 + wm * 64 + i * 16 + lg * 4;
    const int bb = gm >> 12;          // /SEQ
    const int ss = gm & (SEQ - 1);
#pragma unroll
    for (int j = 0; j < 4; ++j) {
      const int gn = n0 + wn * 64 + j * 16 + l16;
      const int hh = gn >> 6, dd = gn & (HD - 1);
      const float bv = bias[gn];
      if (z == 2) {
        union { u16 u[4]; uint2 v; } pk;
#pragma unroll
        for (int r = 0; r < 4; ++r) pk.u[r] = f2bf(acc[i][j][r] + bv);
        *reinterpret_cast<uint2*>(
            oz + ((size_t)(bb * NH + hh) * HD + dd) * SEQ + ss) = pk.v;
      } else {
        u16* op = oz + ((size_t)(bb * NH + hh) * SEQ + ss) * HD + dd;
#pragma unroll
        for (int r = 0; r < 4; ++r)
          op[(size_t)r * HD] = f2bf((acc[i][j][r] + bv) * qscale);
      }
    }
  }
}

// ---------------------------------------------------------------- out proj
__global__ __launch_bounds__(256) void gemm_out_kernel(
    const u16* __restrict__ A, const u16* __restrict__ W,
    const float* __restrict__ bias, float* __restrict__ Out) {
  __shared__ __align__(16) u16 As[128 * 32];
  __shared__ __align__(16) u16 Bs[128 * 32];

  const int tid = threadIdx.x;
  const int w = tid >> 6, lane = tid & 63;
  const int l16 = lane & 15, lg = lane >> 4;
  const int wm = w >> 1, wn = w & 1;

  const int m0 = blockIdx.x * 128;
  const int n0 = blockIdx.y * 128;

  f32x4 acc[4][4];
#pragma unroll
  for (int i = 0; i < 4; ++i)
#pragma unroll
    for (int j = 0; j < 4; ++j) {
      acc[i][j][0] = 0.f; acc[i][j][1] = 0.f;
      acc[i][j][2] = 0.f; acc[i][j][3] = 0.f;
    }

  for (int k0 = 0; k0 < DM; k0 += 32) {
#pragma unroll
    for (int i = 0; i < 2; ++i) {
      const int c = (w * 2 + i) * 64 + lane;
      const int m = c >> 2, kc = c & 3;
      GLDS16(A + (size_t)(m0 + m) * DM + (k0 + kc * 8),
             As + (size_t)(w * 2 + i) * 512);
      GLDS16(W + (size_t)(n0 + m) * DM + (k0 + kc * 8),
             Bs + (size_t)(w * 2 + i) * 512);
    }
    __syncthreads();
    bf16x8 af[4], bfv[4];
#pragma unroll
    for (int i = 0; i < 4; ++i)
      af[i] = ldb8(As + (wm * 64 + i * 16 + l16) * 32 + lg * 8);
#pragma unroll
    for (int j = 0; j < 4; ++j)
      bfv[j] = ldb8(Bs + (wn * 64 + j * 16 + l16) * 32 + lg * 8);
#pragma unroll
    for (int i = 0; i < 4; ++i)
#pragma unroll
      for (int j = 0; j < 4; ++j)
        acc[i][j] = mfma16(af[i], bfv[j], acc[i][j]);
    __syncthreads();
  }

#pragma unroll
  for (int i = 0; i < 4; ++i) {
    const int gm = m0 + wm * 64 + i * 16 + lg * 4;
#pragma unroll
    for (int j = 0; j < 4; ++j) {
      const int gn = n0 + wn * 64 + j * 16 + l16;
      const float bv = bias[gn];
      float* op = Out + (size_t)gm * DM + gn;
#pragma unroll
      for (int r = 0; r < 4; ++r)
        op[(size_t)r * DM] = acc[i][j][r] + bv;
    }
  }
}

// ---------------------------------------------------------------- attention
// KV-split work schedule: per bh, 48 block-slots j:
//   j <  16: q-tile qt=j, full kv range [0, 2qt+2), direct bf16 store.
//   j >= 16: s=j-16; qt=16+s/2; half=s&1; kv chunk [half*(qt+1), (half+1)*(qt+1)),
//            f32 atomicAdd partials (fixed-base softmax => partials additive;
//            exactly 2 adds per location => bit-deterministic).
// blockIdx -> (rank desc by work, bh); 1152 blocks, max 33 tile-iters each.
__global__ __launch_bounds__(256) void attn_kernel(
    const u16* __restrict__ Qg, const u16* __restrict__ Kg,
    const u16* __restrict__ VTg, u16* __restrict__ Og,
    float* __restrict__ PO, float* __restrict__ PL) {
  __shared__ __align__(16) u16 Kt[2][64][72];   // [buf][kv][d], +8 pad
  __shared__ __align__(16) u16 Vt[2][64][72];   // [buf][d][kv], +8 pad (V^T)

  const int tid = threadIdx.x;
  const int w = tid >> 6, lane = tid & 63;
  const int l32 = lane & 31, hi = lane >> 5;

  const int idx = blockIdx.x;            // 0..1151
  const int rank = idx / 24;             // 0..47, ascending = work descending
  const int bh = idx % 24;
  int j;
  if (rank < 40) {
    const int g = rank / 5, r5 = rank % 5;
    j = (r5 == 0) ? (15 - g)
                  : ((r5 < 3) ? (46 - 4 * g + (r5 - 1))
                              : (44 - 4 * g + (r5 - 3)));
  } else {
    j = 47 - rank;
  }
  int qt, t0, t1;
  bool direct;
  if (j < 16) {
    qt = j; t0 = 0; t1 = 2 * j + 2; direct = true;
  } else {
    const int s = j - 16;
    qt = 16 + (s >> 1);
    const int L = qt + 1;
    t0 = (s & 1) * L; t1 = t0 + L; direct = false;
  }
  const int bb = bh / NH, hh = bh % NH;

  const u16* Qp = Qg + (size_t)bh * SEQ * HD;
  const u16* Kp = Kg + (size_t)bh * SEQ * HD;
  const u16* VTp = VTg + (size_t)bh * HD * SEQ;

  const int qw0 = qt * 128 + w * 32;
  const int qlane = qw0 + l32;

  // Q fragments (B-operand): qf[c][j] = Q[q][c*16 + hi*8 + j]  (pre-scaled)
  bf16x8 qf[4];
#pragma unroll
  for (int c = 0; c < 4; ++c)
    qf[c] = ldb8(Qp + (size_t)qlane * HD + c * 16 + hi * 8);

  f32x16 oacc[2];  // O^T[32*db + crow(reg,hi)][q=l32]
#pragma unroll
  for (int db = 0; db < 2; ++db)
#pragma unroll
    for (int r = 0; r < 16; ++r) oacc[db][r] = 0.f;
  float lsum = 0.f;

  // staging coords: 8 threads per 64-elem row, rows srow and srow+32
  const int srow = tid >> 3;        // 0..31
  const int sc8 = (tid & 7) * 8;

  // ---- prologue: stage tile t0 into buffer 0
  {
    const int kb = t0 * 64;
    uint4 a = *reinterpret_cast<const uint4*>(
        Kp + (size_t)(kb + srow) * HD + sc8);
    uint4 b = *reinterpret_cast<const uint4*>(
        Kp + (size_t)(kb + srow + 32) * HD + sc8);
    uint4 c = *reinterpret_cast<const uint4*>(
        VTp + (size_t)srow * SEQ + kb + sc8);
    uint4 d = *reinterpret_cast<const uint4*>(
        VTp + (size_t)(srow + 32) * SEQ + kb + sc8);
    *reinterpret_cast<uint4*>(&Kt[0][srow][sc8]) = a;
    *reinterpret_cast<uint4*>(&Kt[0][srow + 32][sc8]) = b;
    *reinterpret_cast<uint4*>(&Vt[0][srow][sc8]) = c;
    *reinterpret_cast<uint4*>(&Vt[0][srow + 32][sc8]) = d;
  }

  int cur = 0;
  for (int t = t0; t < t1; ++t) {
    const int kv0 = t * 64;
    const bool pf = (t + 1 < t1);
    uint4 nK0, nK1, nV0, nV1;
    if (pf) {  // prefetch next tile to regs (latency spans barrier + QK)
      const int nk = kv0 + 64;
      nK0 = *reinterpret_cast<const uint4*>(
          Kp + (size_t)(nk + srow) * HD + sc8);
      nK1 = *reinterpret_cast<const uint4*>(
          Kp + (size_t)(nk + srow + 32) * HD + sc8);
      nV0 = *reinterpret_cast<const uint4*>(
          VTp + (size_t)srow * SEQ + nk + sc8);
      nV1 = *reinterpret_cast<const uint4*>(
          VTp + (size_t)(srow + 32) * SEQ + nk + sc8);
    }
    __syncthreads();  // buf[cur] writes visible; prev reads of buf[cur^1] done

    const bool active = (kv0 <= qw0 + 31);
    f32x16 st[2];
    if (active) {
      // ---- QK^T (swapped): st[b] = S^T[kv=32b+crow][q]
      __builtin_amdgcn_s_setprio(1);
#pragma unroll
      for (int b = 0; b < 2; ++b) {
#pragma unroll
        for (int r = 0; r < 16; ++r) st[b][r] = 0.f;
#pragma unroll
        for (int c = 0; c < 4; ++c) {
          bf16x8 kf = ldb8(&Kt[cur][b * 32 + l32][c * 16 + hi * 8]);
          st[b] = mfma32(kf, qf[c], st[b]);
        }
      }
      __builtin_amdgcn_s_setprio(0);

      // ---- causal mask (diagonal tiles only)
      if (kv0 + 63 > qw0) {
#pragma unroll
        for (int b = 0; b < 2; ++b)
#pragma unroll
          for (int r = 0; r < 16; ++r) {
            const int kvi = kv0 + b * 32 + (r & 3) + 8 * (r >> 2) + 4 * hi;
            if (kvi > qlane) st[b][r] = -__builtin_inff();
          }
      }

      // ---- fixed-base exp (log2 units): P = exp2(st), masked -> exp2(-inf)=0
#pragma unroll
      for (int r = 0; r < 16; ++r) {
        st[0][r] = exp2f(st[0][r]);
        st[1][r] = exp2f(st[1][r]);
      }
      // ---- packed row-sum (v_pk_add_f32 tree)
      {
        const f32x2* h0 = reinterpret_cast<const f32x2*>(&st[0]);
        const f32x2* h1 = reinterpret_cast<const f32x2*>(&st[1]);
        f32x2 t2[8];
#pragma unroll
        for (int i = 0; i < 8; ++i) t2[i] = pkadd(h0[i], h1[i]);
#pragma unroll
        for (int i = 0; i < 4; ++i) t2[i] = pkadd(t2[i], t2[i + 4]);
        t2[0] = pkadd(t2[0], t2[2]);
        t2[1] = pkadd(t2[1], t2[3]);
        t2[0] = pkadd(t2[0], t2[1]);
        lsum += t2[0][0] + t2[0][1];
      }
    }

    if (pf) {  // write next tile into the other buffer (latency under PV)
      *reinterpret_cast<uint4*>(&Kt[cur ^ 1][srow][sc8]) = nK0;
      *reinterpret_cast<uint4*>(&Kt[cur ^ 1][srow + 32][sc8]) = nK1;
      *reinterpret_cast<uint4*>(&Vt[cur ^ 1][srow][sc8]) = nV0;
      *reinterpret_cast<uint4*>(&Vt[cur ^ 1][srow + 32][sc8]) = nV1;
    }

    if (active) {
      // ---- pack P to bf16 fragments (permlane half-swap) and PV
#pragma unroll
      for (int b = 0; b < 2; ++b) {
#pragma unroll
        for (int h = 0; h < 2; ++h) {  // kv 16-chunk c = 2b + h
          u32 a0 = cvtpk(st[b][h * 8 + 0], st[b][h * 8 + 1]);
          u32 a1 = cvtpk(st[b][h * 8 + 2], st[b][h * 8 + 3]);
          u32 a2 = cvtpk(st[b][h * 8 + 4], st[b][h * 8 + 5]);
          u32 a3 = cvtpk(st[b][h * 8 + 6], st[b][h * 8 + 7]);
          pl32swap(a0, a2);  // distinct values -> distinct regs
          pl32swap(a1, a3);
          union { u32 w[4]; bf16x8 v; } pb;
          pb.w[0] = a0; pb.w[1] = a1; pb.w[2] = a2; pb.w[3] = a3;
          const int c = 2 * b + h;
          __builtin_amdgcn_s_setprio(1);
#pragma unroll
          for (int db = 0; db < 2; ++db) {
            bf16x8 vf = ldb8(&Vt[cur][db * 32 + l32][c * 16 + hi * 8]);
            oacc[db] = mfma32(vf, pb.v, oacc[db]);
          }
          __builtin_amdgcn_s_setprio(0);
        }
      }
    }
    cur ^= 1;
  }

  const float ltot = lsum + __shfl_xor(lsum, 32);

  if (direct) {
    // ---- normalize, store O[q][d] bf16
    const float linv = 1.f / ltot;
    u16* Op = Og + ((size_t)bb * SEQ + qlane) * DM + hh * HD;
#pragma unroll
    for (int db = 0; db < 2; ++db)
#pragma unroll
      for (int r = 0; r < 16; r += 2) {
        const int d = db * 32 + (r & 3) + 8 * (r >> 2) + 4 * hi;
        u32 pk = cvtpk(oacc[db][r] * linv, oacc[db][r + 1] * linv);
        *reinterpret_cast<u32*>(Op + d) = pk;
      }
  } else {
    // ---- accumulate f32 partials (2 adds per location total)
    const int grp = bh * 16 + (qt - 16);
    const int qrow = w * 32 + l32;
    float* pbase = PO + ((size_t)grp * 128 + qrow) * 64;
#pragma unroll
    for (int db = 0; db < 2; ++db)
#pragma unroll
      for (int r = 0; r < 16; ++r) {
        const int d = db * 32 + (r & 3) + 8 * (r >> 2) + 4 * hi;
        unsafeAtomicAdd(pbase + d, oacc[db][r]);
      }
    if (hi == 0) unsafeAtomicAdd(PL + grp * 128 + qrow, ltot);
  }
}

// ---------------------------------------------------------------- combine
// 384 blocks: (bh, qt16). Normalize split-group partials, write PRE bf16.
__global__ __launch_bounds__(256) void combine_kernel(
    const float* __restrict__ PO, const float* __restrict__ PL,
    u16* __restrict__ Og) {
  const int blk = blockIdx.x;               // 0..383
  const int bh = blk % 24, qt16 = blk / 24;
  const int bb = bh / NH, hh = bh % NH;
  const int tid = threadIdx.x;
  const int q = tid >> 1;                   // 0..127
  const int d0 = (tid & 1) * 32;
  const int grp = bh * 16 + qt16;
  const float* po = PO + ((size_t)grp * 128 + q) * 64 + d0;
  const float linv = 1.f / PL[grp * 128 + q];
  const int srow = (16 + qt16) * 128 + q;
  u16* op = Og + ((size_t)bb * SEQ + srow) * DM + hh * HD + d0;
  u32 pk[16];
#pragma unroll
  for (int i = 0; i < 16; ++i)
    pk[i] = cvtpk(po[2 * i] * linv, po[2 * i + 1] * linv);
#pragma unroll
  for (int i = 0; i < 4; ++i)
    reinterpret_cast<uint4*>(op)[i] = *reinterpret_cast<const uint4*>(&pk[4 * i]);
}

// ---------------------------------------------------------------- launcher
extern "C" void kernel_launch(void* const* d_in, const int* in_sizes, int n_in,
                              void* d_out, int out_size, void* d_ws,
                              size_t ws_size, hipStream_t stream) {
  const float* x  = (const float*)d_in[0];
  const float* Wq = (const float*)d_in[1];
  const float* bq = (const float*)d_in[2];
  const float* Wk = (const float*)d_in[3];
  const float* bk = (const float*)d_in[4];
  const float* Wv = (const float*)d_in[5];
  const float* bv = (const float*)d_in[6];
  const float* Wo = (const float*)d_in[7];
  const float* bo = (const float*)d_in[8];
  float* out = (float*)d_out;

  u16* xb   = (u16*)d_ws;                       // [8192][768] bf16 (dead after
                                                //  gemm_qkv; reused as PO f32)
  u16* Wall = xb + (size_t)MR * DM;             // 4 x [768][768] bf16
  u16* QKV  = Wall + (size_t)4 * DM * DM;       // Q,K: [bh][s][64]; V: [bh][d][s]
  u16* PRE  = QKV + (size_t)3 * MR * DM;        // [8192][768] bf16
  float* PO = (float*)d_ws;                     // 384 grp x 128 q x 64 d f32
  float* PL = (float*)(PRE + (size_t)MR * DM);  // 384 grp x 128 q f32

  cvt_kernel<<<dim3(MR * DM / 8 / 256), 256, 0, stream>>>(x, xb, MR * DM / 8);
  cvt_w_kernel<<<dim3(DM * DM / 8 / 256, 4), 256, 0, stream>>>(Wq, Wk, Wv, Wo,
                                                               Wall);
  gemm_qkv_kernel<<<dim3(MR / 128, DM / 128, 3), 256, 0, stream>>>(
      xb, Wall, bq, bk, bv, QKV);
  hipMemsetAsync(PO, 0, (size_t)384 * 128 * 64 * 4, stream);
  hipMemsetAsync(PL, 0, (size_t)384 * 128 * 4, stream);
  attn_kernel<<<dim3(1152), 256, 0, stream>>>(
      QKV, QKV + (size_t)MR * DM, QKV + (size_t)2 * MR * DM, PRE, PO, PL);
  combine_kernel<<<dim3(384), 256, 0, stream>>>(PO, PL, PRE);
  gemm_out_kernel<<<dim3(MR / 128, DM / 128), 256, 0, stream>>>(
      PRE, Wall + (size_t)3 * DM * DM, bo, out);
}

// Round 9
// 200.683 us; speedup vs baseline: 1.5575x; 1.5575x over previous
//
#include <hip/hip_runtime.h>

typedef unsigned short u16;
typedef unsigned int u32;
typedef __bf16 bf16_t;
typedef bf16_t bf16x8 __attribute__((ext_vector_type(8)));
typedef float f32x2 __attribute__((ext_vector_type(2)));
typedef float f32x4 __attribute__((ext_vector_type(4)));
typedef float f32x16 __attribute__((ext_vector_type(16)));

#define DM 768
#define HD 64
#define NH 12
#define NB 2
#define SEQ 4096
#define MR (NB * SEQ)  // 8192

#define SCL2E_F (0.125f * 1.44269504088896340736f)  // 1/sqrt(64) * log2(e)

__device__ __forceinline__ u16 f2bf(float f) {
  union { float f; u32 u; } v;
  v.f = f;
  u32 r = v.u + 0x7FFFu + ((v.u >> 16) & 1u);  // RNE, finite inputs only
  return (u16)(r >> 16);
}

// hardware pack: lo16 = bf16(a), hi16 = bf16(b)
__device__ __forceinline__ u32 cvtpk(float a, float b) {
  u32 r;
  asm("v_cvt_pk_bf16_f32 %0, %1, %2" : "=v"(r) : "v"(a), "v"(b));
  return r;
}

// half-swap between two DISTINCT registers (never call with identical values):
// a_new = lanes<32 ? a : b[lane-32];  b_new = lanes<32 ? a[lane+32] : b
__device__ __forceinline__ void pl32swap(u32& a, u32& b) {
  asm volatile("v_permlane32_swap_b32 %0, %1" : "+v"(a), "+v"(b));
}

__device__ __forceinline__ f32x2 pkadd(f32x2 a, f32x2 b) {
  f32x2 r;
  asm("v_pk_add_f32 %0, %1, %2" : "=v"(r) : "v"(a), "v"(b));
  return r;
}

__device__ __forceinline__ bf16x8 ldb8(const u16* p) {
  return *reinterpret_cast<const bf16x8*>(p);
}

__device__ __forceinline__ float bf2f(u16 u) {
  union { u32 u; float f; } v;
  v.u = (u32)u << 16;
  return v.f;
}

__device__ __forceinline__ f32x4 mfma16(bf16x8 a, bf16x8 b, f32x4 c) {
  return __builtin_amdgcn_mfma_f32_16x16x32_bf16(a, b, c, 0, 0, 0);
}

__device__ __forceinline__ f32x16 mfma32(bf16x8 a, bf16x8 b, f32x16 c) {
  return __builtin_amdgcn_mfma_f32_32x32x16_bf16(a, b, c, 0, 0, 0);
}

#define GLDS16(g, l)                                              \
  __builtin_amdgcn_global_load_lds(                               \
      (const __attribute__((address_space(1))) void*)(g),         \
      (__attribute__((address_space(3))) void*)(l), 16, 0, 0)

// descending-work slot order (48 slots per bh; see attn_kernel comment)
__device__ __constant__ unsigned char kOrder[48] = {
    15, 46, 47, 44, 45, 14, 42, 43, 40, 41, 13, 38, 39, 36, 37, 12,
    34, 35, 32, 33, 11, 30, 31, 28, 29, 10, 26, 27, 24, 25, 9,  22,
    23, 20, 21, 8,  18, 19, 16, 17, 7,  6,  5,  4,  3,  2,  1,  0};

// ---------------------------------------------------------------- converts
__global__ __launch_bounds__(256) void cvt_kernel(const float* __restrict__ src,
                                                  u16* __restrict__ dst, int n8) {
  int i = blockIdx.x * 256 + threadIdx.x;
  if (i >= n8) return;
  const float4* s = reinterpret_cast<const float4*>(src) + (size_t)i * 2;
  float4 a = s[0], b = s[1];
  union { u16 u[8]; uint4 v; } o;
  o.u[0] = f2bf(a.x); o.u[1] = f2bf(a.y); o.u[2] = f2bf(a.z); o.u[3] = f2bf(a.w);
  o.u[4] = f2bf(b.x); o.u[5] = f2bf(b.y); o.u[6] = f2bf(b.z); o.u[7] = f2bf(b.w);
  reinterpret_cast<uint4*>(dst)[i] = o.v;
}

__global__ __launch_bounds__(256) void cvt_w_kernel(const float* __restrict__ w0,
                                                    const float* __restrict__ w1,
                                                    const float* __restrict__ w2,
                                                    const float* __restrict__ w3,
                                                    u16* __restrict__ dst) {
  const float* src = (blockIdx.y == 0) ? w0 : (blockIdx.y == 1) ? w1
                   : (blockIdx.y == 2) ? w2 : w3;
  u16* d = dst + (size_t)blockIdx.y * DM * DM;
  int i = blockIdx.x * 256 + threadIdx.x;
  const float4* s = reinterpret_cast<const float4*>(src) + (size_t)i * 2;
  float4 a = s[0], b = s[1];
  union { u16 u[8]; uint4 v; } o;
  o.u[0] = f2bf(a.x); o.u[1] = f2bf(a.y); o.u[2] = f2bf(a.z); o.u[3] = f2bf(a.w);
  o.u[4] = f2bf(b.x); o.u[5] = f2bf(b.y); o.u[6] = f2bf(b.z); o.u[7] = f2bf(b.w);
  reinterpret_cast<uint4*>(d)[i] = o.v;
}

// ---------------------------------------------------------------- QKV GEMM
// C[m,n] = sum_k A[m,k] * W[n,k] + bias[n]
// z==0 (Q): scaled by SCL2E, layout [bh][s][64]
// z==1 (K): layout [bh][s][64]
// z==2 (V): TRANSPOSED layout [bh][d][s]  (V^T, packed uint2 stores)
__global__ __launch_bounds__(256) void gemm_qkv_kernel(
    const u16* __restrict__ A, const u16* __restrict__ Wall,
    const float* __restrict__ b0, const float* __restrict__ b1,
    const float* __restrict__ b2, u16* __restrict__ O) {
  __shared__ __align__(16) u16 As[128 * 32];
  __shared__ __align__(16) u16 Bs[128 * 32];

  const int tid = threadIdx.x;
  const int w = tid >> 6, lane = tid & 63;
  const int l16 = lane & 15, lg = lane >> 4;
  const int wm = w >> 1, wn = w & 1;

  const int m0 = blockIdx.x * 128;
  const int n0 = blockIdx.y * 128;
  const int z = blockIdx.z;

  const u16* W = Wall + (size_t)z * DM * DM;
  const float* bias = (z == 0) ? b0 : ((z == 1) ? b1 : b2);
  u16* oz = O + (size_t)z * MR * DM;
  const float qscale = (z == 0) ? SCL2E_F : 1.f;

  f32x4 acc[4][4];
#pragma unroll
  for (int i = 0; i < 4; ++i)
#pragma unroll
    for (int j = 0; j < 4; ++j) {
      acc[i][j][0] = 0.f; acc[i][j][1] = 0.f;
      acc[i][j][2] = 0.f; acc[i][j][3] = 0.f;
    }

  for (int k0 = 0; k0 < DM; k0 += 32) {
#pragma unroll
    for (int i = 0; i < 2; ++i) {
      const int c = (w * 2 + i) * 64 + lane;
      const int m = c >> 2, kc = c & 3;
      GLDS16(A + (size_t)(m0 + m) * DM + (k0 + kc * 8),
             As + (size_t)(w * 2 + i) * 512);
      GLDS16(W + (size_t)(n0 + m) * DM + (k0 + kc * 8),
             Bs + (size_t)(w * 2 + i) * 512);
    }
    __syncthreads();
    bf16x8 af[4], bfv[4];
#pragma unroll
    for (int i = 0; i < 4; ++i)
      af[i] = ldb8(As + (wm * 64 + i * 16 + l16) * 32 + lg * 8);
#pragma unroll
    for (int j = 0; j < 4; ++j)
      bfv[j] = ldb8(Bs + (wn * 64 + j * 16 + l16) * 32 + lg * 8);
#pragma unroll
    for (int i = 0; i < 4; ++i)
#pragma unroll
      for (int j = 0; j < 4; ++j)
        acc[i][j] = mfma16(af[i], bfv[j], acc[i][j]);
    __syncthreads();
  }

#pragma unroll
  for (int i = 0; i < 4; ++i) {
    const int gm = m0 + wm * 64 + i * 16 + lg * 4;
    const int bb = gm >> 12;          // /SEQ
    const int ss = gm & (SEQ - 1);
#pragma unroll
    for (int j = 0; j < 4; ++j) {
      const int gn = n0 + wn * 64 + j * 16 + l16;
      const int hh = gn >> 6, dd = gn & (HD - 1);
      const float bv = bias[gn];
      if (z == 2) {
        union { u16 u[4]; uint2 v; } pk;
#pragma unroll
        for (int r = 0; r < 4; ++r) pk.u[r] = f2bf(acc[i][j][r] + bv);
        *reinterpret_cast<uint2*>(
            oz + ((size_t)(bb * NH + hh) * HD + dd) * SEQ + ss) = pk.v;
      } else {
        u16* op = oz + ((size_t)(bb * NH + hh) * SEQ + ss) * HD + dd;
#pragma unroll
        for (int r = 0; r < 4; ++r)
          op[(size_t)r * HD] = f2bf((acc[i][j][r] + bv) * qscale);
      }
    }
  }
}

// ---------------------------------------------------------------- out proj
__global__ __launch_bounds__(256) void gemm_out_kernel(
    const u16* __restrict__ A, const u16* __restrict__ W,
    const float* __restrict__ bias, float* __restrict__ Out) {
  __shared__ __align__(16) u16 As[128 * 32];
  __shared__ __align__(16) u16 Bs[128 * 32];

  const int tid = threadIdx.x;
  const int w = tid >> 6, lane = tid & 63;
  const int l16 = lane & 15, lg = lane >> 4;
  const int wm = w >> 1, wn = w & 1;

  const int m0 = blockIdx.x * 128;
  const int n0 = blockIdx.y * 128;

  f32x4 acc[4][4];
#pragma unroll
  for (int i = 0; i < 4; ++i)
#pragma unroll
    for (int j = 0; j < 4; ++j) {
      acc[i][j][0] = 0.f; acc[i][j][1] = 0.f;
      acc[i][j][2] = 0.f; acc[i][j][3] = 0.f;
    }

  for (int k0 = 0; k0 < DM; k0 += 32) {
#pragma unroll
    for (int i = 0; i < 2; ++i) {
      const int c = (w * 2 + i) * 64 + lane;
      const int m = c >> 2, kc = c & 3;
      GLDS16(A + (size_t)(m0 + m) * DM + (k0 + kc * 8),
             As + (size_t)(w * 2 + i) * 512);
      GLDS16(W + (size_t)(n0 + m) * DM + (k0 + kc * 8),
             Bs + (size_t)(w * 2 + i) * 512);
    }
    __syncthreads();
    bf16x8 af[4], bfv[4];
#pragma unroll
    for (int i = 0; i < 4; ++i)
      af[i] = ldb8(As + (wm * 64 + i * 16 + l16) * 32 + lg * 8);
#pragma unroll
    for (int j = 0; j < 4; ++j)
      bfv[j] = ldb8(Bs + (wn * 64 + j * 16 + l16) * 32 + lg * 8);
#pragma unroll
    for (int i = 0; i < 4; ++i)
#pragma unroll
      for (int j = 0; j < 4; ++j)
        acc[i][j] = mfma16(af[i], bfv[j], acc[i][j]);
    __syncthreads();
  }

#pragma unroll
  for (int i = 0; i < 4; ++i) {
    const int gm = m0 + wm * 64 + i * 16 + lg * 4;
#pragma unroll
    for (int j = 0; j < 4; ++j) {
      const int gn = n0 + wn * 64 + j * 16 + l16;
      const float bv = bias[gn];
      float* op = Out + (size_t)gm * DM + gn;
#pragma unroll
      for (int r = 0; r < 4; ++r)
        op[(size_t)r * DM] = acc[i][j][r] + bv;
    }
  }
}

// ---------------------------------------------------------------- attention
// KV-split schedule, NO atomics. Per bh, 48 slots j:
//   j <  16: q-tile qt=j, full kv [0, 2qt+2), direct bf16 store to PRE.
//   j >= 16: s=j-16; qt=16+s/2; half=s&1; kv chunk [half*(qt+1),(half+1)*(qt+1));
//            partial O (raw, unnormalized) -> bf16 plain stores into PO[grp][half],
//            partial l -> f32 PL[grp][half]. Fixed-base softmax => additive.
// Slots dispatched descending-work via kOrder (max 33, avg 22 tile-iters).
__global__ __launch_bounds__(256) void attn_kernel(
    const u16* __restrict__ Qg, const u16* __restrict__ Kg,
    const u16* __restrict__ VTg, u16* __restrict__ Og,
    u16* __restrict__ PO, float* __restrict__ PL) {
  __shared__ __align__(16) u16 Kt[2][64][72];   // [buf][kv][d], +8 pad
  __shared__ __align__(16) u16 Vt[2][64][72];   // [buf][d][kv], +8 pad (V^T)

  const int tid = threadIdx.x;
  const int w = tid >> 6, lane = tid & 63;
  const int l32 = lane & 31, hi = lane >> 5;

  const int idx = blockIdx.x;            // 0..1151
  const int rank = idx / 24;             // 0..47
  const int bh = idx % 24;
  const int j = kOrder[rank];
  int qt, t0, t1, half = 0;
  bool direct;
  if (j < 16) {
    qt = j; t0 = 0; t1 = 2 * j + 2; direct = true;
  } else {
    const int s = j - 16;
    qt = 16 + (s >> 1);
    half = s & 1;
    const int L = qt + 1;
    t0 = half * L; t1 = t0 + L; direct = false;
  }
  const int bb = bh / NH, hh = bh % NH;

  const u16* Qp = Qg + (size_t)bh * SEQ * HD;
  const u16* Kp = Kg + (size_t)bh * SEQ * HD;
  const u16* VTp = VTg + (size_t)bh * HD * SEQ;

  const int qw0 = qt * 128 + w * 32;
  const int qlane = qw0 + l32;

  // Q fragments (B-operand): qf[c][j] = Q[q][c*16 + hi*8 + j]  (pre-scaled)
  bf16x8 qf[4];
#pragma unroll
  for (int c = 0; c < 4; ++c)
    qf[c] = ldb8(Qp + (size_t)qlane * HD + c * 16 + hi * 8);

  f32x16 oacc[2];  // O^T[32*db + crow(reg,hi)][q=l32]
#pragma unroll
  for (int db = 0; db < 2; ++db)
#pragma unroll
    for (int r = 0; r < 16; ++r) oacc[db][r] = 0.f;
  float lsum = 0.f;

  // staging coords: 8 threads per 64-elem row, rows srow and srow+32
  const int srow = tid >> 3;        // 0..31
  const int sc8 = (tid & 7) * 8;

  // ---- prologue: stage tile t0 into buffer 0
  {
    const int kb = t0 * 64;
    uint4 a = *reinterpret_cast<const uint4*>(
        Kp + (size_t)(kb + srow) * HD + sc8);
    uint4 b = *reinterpret_cast<const uint4*>(
        Kp + (size_t)(kb + srow + 32) * HD + sc8);
    uint4 c = *reinterpret_cast<const uint4*>(
        VTp + (size_t)srow * SEQ + kb + sc8);
    uint4 d = *reinterpret_cast<const uint4*>(
        VTp + (size_t)(srow + 32) * SEQ + kb + sc8);
    *reinterpret_cast<uint4*>(&Kt[0][srow][sc8]) = a;
    *reinterpret_cast<uint4*>(&Kt[0][srow + 32][sc8]) = b;
    *reinterpret_cast<uint4*>(&Vt[0][srow][sc8]) = c;
    *reinterpret_cast<uint4*>(&Vt[0][srow + 32][sc8]) = d;
  }

  int cur = 0;
  for (int t = t0; t < t1; ++t) {
    const int kv0 = t * 64;
    const bool pf = (t + 1 < t1);
    uint4 nK0, nK1, nV0, nV1;
    if (pf) {  // prefetch next tile to regs (latency spans barrier + QK)
      const int nk = kv0 + 64;
      nK0 = *reinterpret_cast<const uint4*>(
          Kp + (size_t)(nk + srow) * HD + sc8);
      nK1 = *reinterpret_cast<const uint4*>(
          Kp + (size_t)(nk + srow + 32) * HD + sc8);
      nV0 = *reinterpret_cast<const uint4*>(
          VTp + (size_t)srow * SEQ + nk + sc8);
      nV1 = *reinterpret_cast<const uint4*>(
          VTp + (size_t)(srow + 32) * SEQ + nk + sc8);
    }
    __syncthreads();  // buf[cur] writes visible; prev reads of buf[cur^1] done

    const bool active = (kv0 <= qw0 + 31);
    f32x16 st[2];
    if (active) {
      // ---- QK^T (swapped): st[b] = S^T[kv=32b+crow][q]
      __builtin_amdgcn_s_setprio(1);
#pragma unroll
      for (int b = 0; b < 2; ++b) {
#pragma unroll
        for (int r = 0; r < 16; ++r) st[b][r] = 0.f;
#pragma unroll
        for (int c = 0; c < 4; ++c) {
          bf16x8 kf = ldb8(&Kt[cur][b * 32 + l32][c * 16 + hi * 8]);
          st[b] = mfma32(kf, qf[c], st[b]);
        }
      }
      __builtin_amdgcn_s_setprio(0);

      // ---- causal mask (diagonal tiles only)
      if (kv0 + 63 > qw0) {
#pragma unroll
        for (int b = 0; b < 2; ++b)
#pragma unroll
          for (int r = 0; r < 16; ++r) {
            const int kvi = kv0 + b * 32 + (r & 3) + 8 * (r >> 2) + 4 * hi;
            if (kvi > qlane) st[b][r] = -__builtin_inff();
          }
      }

      // ---- fixed-base exp (log2 units): P = exp2(st), masked -> exp2(-inf)=0
#pragma unroll
      for (int r = 0; r < 16; ++r) {
        st[0][r] = exp2f(st[0][r]);
        st[1][r] = exp2f(st[1][r]);
      }
      // ---- packed row-sum (v_pk_add_f32 tree)
      {
        const f32x2* h0 = reinterpret_cast<const f32x2*>(&st[0]);
        const f32x2* h1 = reinterpret_cast<const f32x2*>(&st[1]);
        f32x2 t2[8];
#pragma unroll
        for (int i = 0; i < 8; ++i) t2[i] = pkadd(h0[i], h1[i]);
#pragma unroll
        for (int i = 0; i < 4; ++i) t2[i] = pkadd(t2[i], t2[i + 4]);
        t2[0] = pkadd(t2[0], t2[2]);
        t2[1] = pkadd(t2[1], t2[3]);
        t2[0] = pkadd(t2[0], t2[1]);
        lsum += t2[0][0] + t2[0][1];
      }
    }

    if (pf) {  // write next tile into the other buffer (latency under PV)
      *reinterpret_cast<uint4*>(&Kt[cur ^ 1][srow][sc8]) = nK0;
      *reinterpret_cast<uint4*>(&Kt[cur ^ 1][srow + 32][sc8]) = nK1;
      *reinterpret_cast<uint4*>(&Vt[cur ^ 1][srow][sc8]) = nV0;
      *reinterpret_cast<uint4*>(&Vt[cur ^ 1][srow + 32][sc8]) = nV1;
    }

    if (active) {
      // ---- pack P to bf16 fragments (permlane half-swap) and PV
#pragma unroll
      for (int b = 0; b < 2; ++b) {
#pragma unroll
        for (int h = 0; h < 2; ++h) {  // kv 16-chunk c = 2b + h
          u32 a0 = cvtpk(st[b][h * 8 + 0], st[b][h * 8 + 1]);
          u32 a1 = cvtpk(st[b][h * 8 + 2], st[b][h * 8 + 3]);
          u32 a2 = cvtpk(st[b][h * 8 + 4], st[b][h * 8 + 5]);
          u32 a3 = cvtpk(st[b][h * 8 + 6], st[b][h * 8 + 7]);
          pl32swap(a0, a2);  // distinct values -> distinct regs
          pl32swap(a1, a3);
          union { u32 w[4]; bf16x8 v; } pb;
          pb.w[0] = a0; pb.w[1] = a1; pb.w[2] = a2; pb.w[3] = a3;
          const int c = 2 * b + h;
          __builtin_amdgcn_s_setprio(1);
#pragma unroll
          for (int db = 0; db < 2; ++db) {
            bf16x8 vf = ldb8(&Vt[cur][db * 32 + l32][c * 16 + hi * 8]);
            oacc[db] = mfma32(vf, pb.v, oacc[db]);
          }
          __builtin_amdgcn_s_setprio(0);
        }
      }
    }
    cur ^= 1;
  }

  const float ltot = lsum + __shfl_xor(lsum, 32);
  const int qrow = w * 32 + l32;

  if (direct) {
    // ---- normalize, store O[q][d] bf16
    const float linv = 1.f / ltot;
    u16* Op = Og + ((size_t)bb * SEQ + qlane) * DM + hh * HD;
#pragma unroll
    for (int db = 0; db < 2; ++db)
#pragma unroll
      for (int r = 0; r < 16; r += 2) {
        const int d = db * 32 + (r & 3) + 8 * (r >> 2) + 4 * hi;
        u32 pk = cvtpk(oacc[db][r] * linv, oacc[db][r + 1] * linv);
        *reinterpret_cast<u32*>(Op + d) = pk;
      }
  } else {
    // ---- raw partial store (plain, coalesced; no atomics)
    const int grp = bh * 16 + (qt - 16);
    u16* pbase = PO + (((size_t)grp * 2 + half) * 128 + qrow) * 64;
#pragma unroll
    for (int db = 0; db < 2; ++db)
#pragma unroll
      for (int r = 0; r < 16; r += 2) {
        const int d = db * 32 + (r & 3) + 8 * (r >> 2) + 4 * hi;
        u32 pk = cvtpk(oacc[db][r], oacc[db][r + 1]);
        *reinterpret_cast<u32*>(pbase + d) = pk;
      }
    if (hi == 0) PL[((size_t)grp * 2 + half) * 128 + qrow] = ltot;
  }
}

// ---------------------------------------------------------------- combine
// 384 blocks = groups (bh, qt-16). Sum two bf16 partials in f32, normalize,
// write PRE rows for q-tiles 16..31.
__global__ __launch_bounds__(256) void combine_kernel(
    const u16* __restrict__ PO, const float* __restrict__ PL,
    u16* __restrict__ Og) {
  const int grp = blockIdx.x;               // 0..383
  const int bh = grp >> 4, qt16 = grp & 15;
  const int bb = bh / NH, hh = bh % NH;
  const int tid = threadIdx.x;
  const int q = tid >> 1;                   // 0..127
  const int d0 = (tid & 1) * 32;
  const u16* p0 = PO + (((size_t)grp * 2 + 0) * 128 + q) * 64 + d0;
  const u16* p1 = PO + (((size_t)grp * 2 + 1) * 128 + q) * 64 + d0;
  const float linv =
      1.f / (PL[((size_t)grp * 2 + 0) * 128 + q] +
             PL[((size_t)grp * 2 + 1) * 128 + q]);
  union { uint4 v[4]; u16 u[32]; } a0, a1;
#pragma unroll
  for (int i = 0; i < 4; ++i) {
    a0.v[i] = reinterpret_cast<const uint4*>(p0)[i];
    a1.v[i] = reinterpret_cast<const uint4*>(p1)[i];
  }
  const int srow = (16 + qt16) * 128 + q;
  u16* op = Og + ((size_t)bb * SEQ + srow) * DM + hh * HD + d0;
  u32 pk[16];
#pragma unroll
  for (int i = 0; i < 16; ++i) {
    const float e0 = (bf2f(a0.u[2 * i]) + bf2f(a1.u[2 * i])) * linv;
    const float e1 = (bf2f(a0.u[2 * i + 1]) + bf2f(a1.u[2 * i + 1])) * linv;
    pk[i] = cvtpk(e0, e1);
  }
#pragma unroll
  for (int i = 0; i < 4; ++i)
    reinterpret_cast<uint4*>(op)[i] = *reinterpret_cast<const uint4*>(&pk[4 * i]);
}

// ---------------------------------------------------------------- launcher
extern "C" void kernel_launch(void* const* d_in, const int* in_sizes, int n_in,
                              void* d_out, int out_size, void* d_ws,
                              size_t ws_size, hipStream_t stream) {
  const float* x  = (const float*)d_in[0];
  const float* Wq = (const float*)d_in[1];
  const float* bq = (const float*)d_in[2];
  const float* Wk = (const float*)d_in[3];
  const float* bk = (const float*)d_in[4];
  const float* Wv = (const float*)d_in[5];
  const float* bv = (const float*)d_in[6];
  const float* Wo = (const float*)d_in[7];
  const float* bo = (const float*)d_in[8];
  float* out = (float*)d_out;

  u16* xb   = (u16*)d_ws;                       // [8192][768] bf16 (dead after
                                                //  gemm_qkv; reused as PO bf16)
  u16* Wall = xb + (size_t)MR * DM;             // 4 x [768][768] bf16
  u16* QKV  = Wall + (size_t)4 * DM * DM;       // Q,K: [bh][s][64]; V: [bh][d][s]
  u16* PRE  = QKV + (size_t)3 * MR * DM;        // [8192][768] bf16
  u16* PO   = (u16*)d_ws;                       // [384][2][128][64] bf16
  float* PL = (float*)(PRE + (size_t)MR * DM);  // [384][2][128] f32

  cvt_kernel<<<dim3(MR * DM / 8 / 256), 256, 0, stream>>>(x, xb, MR * DM / 8);
  cvt_w_kernel<<<dim3(DM * DM / 8 / 256, 4), 256, 0, stream>>>(Wq, Wk, Wv, Wo,
                                                               Wall);
  gemm_qkv_kernel<<<dim3(MR / 128, DM / 128, 3), 256, 0, stream>>>(
      xb, Wall, bq, bk, bv, QKV);
  attn_kernel<<<dim3(1152), 256, 0, stream>>>(
      QKV, QKV + (size_t)MR * DM, QKV + (size_t)2 * MR * DM, PRE, PO, PL);
  combine_kernel<<<dim3(384), 256, 0, stream>>>(PO, PL, PRE);
  gemm_out_kernel<<<dim3(MR / 128, DM / 128), 256, 0, stream>>>(
      PRE, Wall + (size_t)3 * DM * DM, bo, out);
}

// Round 11
// 174.065 us; speedup vs baseline: 1.7956x; 1.1529x over previous
//
#include <hip/hip_runtime.h>

typedef unsigned short u16;
typedef unsigned int u32;
typedef __bf16 bf16_t;
typedef bf16_t bf16x8 __attribute__((ext_vector_type(8)));
typedef float f32x4 __attribute__((ext_vector_type(4)));
typedef float f32x16 __attribute__((ext_vector_type(16)));

#define DM 768
#define HD 64
#define NH 12
#define NB 2
#define SEQ 4096
#define MR (NB * SEQ)  // 8192

#define SCL2E_F (0.125f * 1.44269504088896340736f)  // 1/sqrt(64) * log2(e)

__device__ __forceinline__ u16 f2bf(float f) {
  union { float f; u32 u; } v;
  v.f = f;
  u32 r = v.u + 0x7FFFu + ((v.u >> 16) & 1u);  // RNE, finite inputs only
  return (u16)(r >> 16);
}

// raw v_exp_f32 (no OCML denormal fixup). All consumers of its result MUST be
// compiler-emitted instructions (not inline asm) -- round-10 fail mode.
__device__ __forceinline__ float fexp2(float x) {
  return __builtin_amdgcn_exp2f(x);
}

// pack two f32 -> 2xbf16 in one u32 via compiler-emitted converts (m240:
// faster than hand-written v_cvt_pk asm, and hazard-safe after TRANS ops)
__device__ __forceinline__ u32 pk2(float a, float b) {
  union { bf16_t h[2]; u32 u; } x;
  x.h[0] = (bf16_t)a;
  x.h[1] = (bf16_t)b;
  return x.u;
}

// hardware pack for non-TRANS inputs (epilogue only)
__device__ __forceinline__ u32 cvtpk(float a, float b) {
  u32 r;
  asm("v_cvt_pk_bf16_f32 %0, %1, %2" : "=v"(r) : "v"(a), "v"(b));
  return r;
}

// half-swap between two DISTINCT registers (never call with identical values):
// a_new = lanes<32 ? a : b[lane-32];  b_new = lanes<32 ? a[lane+32] : b
__device__ __forceinline__ void pl32swap(u32& a, u32& b) {
  asm volatile("v_permlane32_swap_b32 %0, %1" : "+v"(a), "+v"(b));
}

__device__ __forceinline__ bf16x8 ldb8(const u16* p) {
  return *reinterpret_cast<const bf16x8*>(p);
}

__device__ __forceinline__ f32x4 mfma16(bf16x8 a, bf16x8 b, f32x4 c) {
  return __builtin_amdgcn_mfma_f32_16x16x32_bf16(a, b, c, 0, 0, 0);
}

__device__ __forceinline__ f32x16 mfma32(bf16x8 a, bf16x8 b, f32x16 c) {
  return __builtin_amdgcn_mfma_f32_32x32x16_bf16(a, b, c, 0, 0, 0);
}

#define GLDS16(g, l)                                              \
  __builtin_amdgcn_global_load_lds(                               \
      (const __attribute__((address_space(1))) void*)(g),         \
      (__attribute__((address_space(3))) void*)(l), 16, 0, 0)

// ---------------------------------------------------------------- converts
__global__ __launch_bounds__(256) void cvt_kernel(const float* __restrict__ src,
                                                  u16* __restrict__ dst, int n8) {
  int i = blockIdx.x * 256 + threadIdx.x;
  if (i >= n8) return;
  const float4* s = reinterpret_cast<const float4*>(src) + (size_t)i * 2;
  float4 a = s[0], b = s[1];
  union { u16 u[8]; uint4 v; } o;
  o.u[0] = f2bf(a.x); o.u[1] = f2bf(a.y); o.u[2] = f2bf(a.z); o.u[3] = f2bf(a.w);
  o.u[4] = f2bf(b.x); o.u[5] = f2bf(b.y); o.u[6] = f2bf(b.z); o.u[7] = f2bf(b.w);
  reinterpret_cast<uint4*>(dst)[i] = o.v;
}

__global__ __launch_bounds__(256) void cvt_w_kernel(const float* __restrict__ w0,
                                                    const float* __restrict__ w1,
                                                    const float* __restrict__ w2,
                                                    const float* __restrict__ w3,
                                                    u16* __restrict__ dst) {
  const float* src = (blockIdx.y == 0) ? w0 : (blockIdx.y == 1) ? w1
                   : (blockIdx.y == 2) ? w2 : w3;
  u16* d = dst + (size_t)blockIdx.y * DM * DM;
  int i = blockIdx.x * 256 + threadIdx.x;
  const float4* s = reinterpret_cast<const float4*>(src) + (size_t)i * 2;
  float4 a = s[0], b = s[1];
  union { u16 u[8]; uint4 v; } o;
  o.u[0] = f2bf(a.x); o.u[1] = f2bf(a.y); o.u[2] = f2bf(a.z); o.u[3] = f2bf(a.w);
  o.u[4] = f2bf(b.x); o.u[5] = f2bf(b.y); o.u[6] = f2bf(b.z); o.u[7] = f2bf(b.w);
  reinterpret_cast<uint4*>(d)[i] = o.v;
}

// ---------------------------------------------------------------- QKV GEMM
// C[m,n] = sum_k A[m,k] * W[n,k] + bias[n]
// z==0 (Q): scaled by SCL2E, layout [bh][s][64]
// z==1 (K): layout [bh][s][64]
// z==2 (V): TRANSPOSED layout [bh][d][s]  (V^T, packed uint2 stores)
__global__ __launch_bounds__(256) void gemm_qkv_kernel(
    const u16* __restrict__ A, const u16* __restrict__ Wall,
    const float* __restrict__ b0, const float* __restrict__ b1,
    const float* __restrict__ b2, u16* __restrict__ O) {
  __shared__ __align__(16) u16 As[128 * 32];
  __shared__ __align__(16) u16 Bs[128 * 32];

  const int tid = threadIdx.x;
  const int w = tid >> 6, lane = tid & 63;
  const int l16 = lane & 15, lg = lane >> 4;
  const int wm = w >> 1, wn = w & 1;

  const int m0 = blockIdx.x * 128;
  const int n0 = blockIdx.y * 128;
  const int z = blockIdx.z;

  const u16* W = Wall + (size_t)z * DM * DM;
  const float* bias = (z == 0) ? b0 : ((z == 1) ? b1 : b2);
  u16* oz = O + (size_t)z * MR * DM;
  const float qscale = (z == 0) ? SCL2E_F : 1.f;

  f32x4 acc[4][4];
#pragma unroll
  for (int i = 0; i < 4; ++i)
#pragma unroll
    for (int j = 0; j < 4; ++j) {
      acc[i][j][0] = 0.f; acc[i][j][1] = 0.f;
      acc[i][j][2] = 0.f; acc[i][j][3] = 0.f;
    }

  for (int k0 = 0; k0 < DM; k0 += 32) {
#pragma unroll
    for (int i = 0; i < 2; ++i) {
      const int c = (w * 2 + i) * 64 + lane;
      const int m = c >> 2, kc = c & 3;
      GLDS16(A + (size_t)(m0 + m) * DM + (k0 + kc * 8),
             As + (size_t)(w * 2 + i) * 512);
      GLDS16(W + (size_t)(n0 + m) * DM + (k0 + kc * 8),
             Bs + (size_t)(w * 2 + i) * 512);
    }
    __syncthreads();
    bf16x8 af[4], bfv[4];
#pragma unroll
    for (int i = 0; i < 4; ++i)
      af[i] = ldb8(As + (wm * 64 + i * 16 + l16) * 32 + lg * 8);
#pragma unroll
    for (int j = 0; j < 4; ++j)
      bfv[j] = ldb8(Bs + (wn * 64 + j * 16 + l16) * 32 + lg * 8);
#pragma unroll
    for (int i = 0; i < 4; ++i)
#pragma unroll
      for (int j = 0; j < 4; ++j)
        acc[i][j] = mfma16(af[i], bfv[j], acc[i][j]);
    __syncthreads();
  }

#pragma unroll
  for (int i = 0; i < 4; ++i) {
    const int gm = m0 + wm * 64 + i * 16 + lg * 4;
    const int bb = gm >> 12;          // /SEQ
    const int ss = gm & (SEQ - 1);
#pragma unroll
    for (int j = 0; j < 4; ++j) {
      const int gn = n0 + wn * 64 + j * 16 + l16;
      const int hh = gn >> 6, dd = gn & (HD - 1);
      const float bv = bias[gn];
      if (z == 2) {
        union { u16 u[4]; uint2 v; } pk;
#pragma unroll
        for (int r = 0; r < 4; ++r) pk.u[r] = f2bf(acc[i][j][r] + bv);
        *reinterpret_cast<uint2*>(
            oz + ((size_t)(bb * NH + hh) * HD + dd) * SEQ + ss) = pk.v;
      } else {
        u16* op = oz + ((size_t)(bb * NH + hh) * SEQ + ss) * HD + dd;
#pragma unroll
        for (int r = 0; r < 4; ++r)
          op[(size_t)r * HD] = f2bf((acc[i][j][r] + bv) * qscale);
      }
    }
  }
}

// ---------------------------------------------------------------- out proj
__global__ __launch_bounds__(256) void gemm_out_kernel(
    const u16* __restrict__ A, const u16* __restrict__ W,
    const float* __restrict__ bias, float* __restrict__ Out) {
  __shared__ __align__(16) u16 As[128 * 32];
  __shared__ __align__(16) u16 Bs[128 * 32];

  const int tid = threadIdx.x;
  const int w = tid >> 6, lane = tid & 63;
  const int l16 = lane & 15, lg = lane >> 4;
  const int wm = w >> 1, wn = w & 1;

  const int m0 = blockIdx.x * 128;
  const int n0 = blockIdx.y * 128;

  f32x4 acc[4][4];
#pragma unroll
  for (int i = 0; i < 4; ++i)
#pragma unroll
    for (int j = 0; j < 4; ++j) {
      acc[i][j][0] = 0.f; acc[i][j][1] = 0.f;
      acc[i][j][2] = 0.f; acc[i][j][3] = 0.f;
    }

  for (int k0 = 0; k0 < DM; k0 += 32) {
#pragma unroll
    for (int i = 0; i < 2; ++i) {
      const int c = (w * 2 + i) * 64 + lane;
      const int m = c >> 2, kc = c & 3;
      GLDS16(A + (size_t)(m0 + m) * DM + (k0 + kc * 8),
             As + (size_t)(w * 2 + i) * 512);
      GLDS16(W + (size_t)(n0 + m) * DM + (k0 + kc * 8),
             Bs + (size_t)(w * 2 + i) * 512);
    }
    __syncthreads();
    bf16x8 af[4], bfv[4];
#pragma unroll
    for (int i = 0; i < 4; ++i)
      af[i] = ldb8(As + (wm * 64 + i * 16 + l16) * 32 + lg * 8);
#pragma unroll
    for (int j = 0; j < 4; ++j)
      bfv[j] = ldb8(Bs + (wn * 64 + j * 16 + l16) * 32 + lg * 8);
#pragma unroll
    for (int i = 0; i < 4; ++i)
#pragma unroll
      for (int j = 0; j < 4; ++j)
        acc[i][j] = mfma16(af[i], bfv[j], acc[i][j]);
    __syncthreads();
  }

#pragma unroll
  for (int i = 0; i < 4; ++i) {
    const int gm = m0 + wm * 64 + i * 16 + lg * 4;
#pragma unroll
    for (int j = 0; j < 4; ++j) {
      const int gn = n0 + wn * 64 + j * 16 + l16;
      const float bv = bias[gn];
      float* op = Out + (size_t)gm * DM + gn;
#pragma unroll
      for (int r = 0; r < 4; ++r)
        op[(size_t)r * DM] = acc[i][j][r] + bv;
    }
  }
}

// ---------------------------------------------------------------- attention
// 1-D grid of 768 blocks, longest-first: qt = 31 - idx/24, bh = idx%24.
// 4 waves x 32 q-rows, KV tile 64, double-buffered K/V LDS, 1 barrier/tile.
// Swapped QK^T (32x32x16): lane holds S^T[kv=crow(reg,hi)][q=lane&31].
// FIXED-BASE softmax with raw v_exp_f32; exp results consumed only by
// compiler-emitted instructions (adds, bf16 casts) -- never inline asm.
__global__ __launch_bounds__(256) void attn_kernel(
    const u16* __restrict__ Qg, const u16* __restrict__ Kg,
    const u16* __restrict__ VTg, u16* __restrict__ Og) {
  __shared__ __align__(16) u16 Kt[2][64][72];   // [buf][kv][d], +8 pad
  __shared__ __align__(16) u16 Vt[2][64][72];   // [buf][d][kv], +8 pad (V^T)

  const int tid = threadIdx.x;
  const int w = tid >> 6, lane = tid & 63;
  const int l32 = lane & 31, hi = lane >> 5;

  const int idx = blockIdx.x;            // 0..767
  const int qt = 31 - (idx / 24);        // longest blocks dispatch first
  const int bh = idx % 24;
  const int bb = bh / NH, hh = bh % NH;

  const u16* Qp = Qg + (size_t)bh * SEQ * HD;
  const u16* Kp = Kg + (size_t)bh * SEQ * HD;
  const u16* VTp = VTg + (size_t)bh * HD * SEQ;

  const int qw0 = qt * 128 + w * 32;
  const int qlane = qw0 + l32;

  // Q fragments (B-operand): qf[c][j] = Q[q][c*16 + hi*8 + j]  (pre-scaled)
  bf16x8 qf[4];
#pragma unroll
  for (int c = 0; c < 4; ++c)
    qf[c] = ldb8(Qp + (size_t)qlane * HD + c * 16 + hi * 8);

  f32x16 oacc[2];  // O^T[32*db + crow(reg,hi)][q=l32]
#pragma unroll
  for (int db = 0; db < 2; ++db)
#pragma unroll
    for (int r = 0; r < 16; ++r) oacc[db][r] = 0.f;
  float lsum = 0.f;

  // staging coords: 8 threads per 64-elem row, rows srow and srow+32
  const int srow = tid >> 3;        // 0..31
  const int sc8 = (tid & 7) * 8;

  // ---- prologue: stage tile 0 into buffer 0
  {
    uint4 a = *reinterpret_cast<const uint4*>(Kp + (size_t)srow * HD + sc8);
    uint4 b = *reinterpret_cast<const uint4*>(
        Kp + (size_t)(srow + 32) * HD + sc8);
    uint4 c = *reinterpret_cast<const uint4*>(
        VTp + (size_t)srow * SEQ + sc8);
    uint4 d = *reinterpret_cast<const uint4*>(
        VTp + (size_t)(srow + 32) * SEQ + sc8);
    *reinterpret_cast<uint4*>(&Kt[0][srow][sc8]) = a;
    *reinterpret_cast<uint4*>(&Kt[0][srow + 32][sc8]) = b;
    *reinterpret_cast<uint4*>(&Vt[0][srow][sc8]) = c;
    *reinterpret_cast<uint4*>(&Vt[0][srow + 32][sc8]) = d;
  }

  const int NT = 2 * qt + 2;
  int cur = 0;
  for (int t = 0; t < NT; ++t) {
    const int kv0 = t * 64;
    const bool pf = (t + 1 < NT);
    uint4 nK0, nK1, nV0, nV1;
    if (pf) {  // prefetch next tile to regs (latency spans barrier + QK)
      const int nk = kv0 + 64;
      nK0 = *reinterpret_cast<const uint4*>(
          Kp + (size_t)(nk + srow) * HD + sc8);
      nK1 = *reinterpret_cast<const uint4*>(
          Kp + (size_t)(nk + srow + 32) * HD + sc8);
      nV0 = *reinterpret_cast<const uint4*>(
          VTp + (size_t)srow * SEQ + nk + sc8);
      nV1 = *reinterpret_cast<const uint4*>(
          VTp + (size_t)(srow + 32) * SEQ + nk + sc8);
    }
    __syncthreads();  // buf[cur] writes visible; prev reads of buf[cur^1] done

    const bool active = (kv0 <= qw0 + 31);
    f32x16 st[2];
    if (active) {
      // ---- QK^T (swapped): st[b] = S^T[kv=32b+crow][q]
      __builtin_amdgcn_s_setprio(1);
#pragma unroll
      for (int b = 0; b < 2; ++b) {
#pragma unroll
        for (int r = 0; r < 16; ++r) st[b][r] = 0.f;
#pragma unroll
        for (int c = 0; c < 4; ++c) {
          bf16x8 kf = ldb8(&Kt[cur][b * 32 + l32][c * 16 + hi * 8]);
          st[b] = mfma32(kf, qf[c], st[b]);
        }
      }
      __builtin_amdgcn_s_setprio(0);

      // ---- causal mask (diagonal tiles only)
      if (kv0 + 63 > qw0) {
#pragma unroll
        for (int b = 0; b < 2; ++b)
#pragma unroll
          for (int r = 0; r < 16; ++r) {
            const int kvi = kv0 + b * 32 + (r & 3) + 8 * (r >> 2) + 4 * hi;
            if (kvi > qlane) st[b][r] = -__builtin_inff();
          }
      }

      // ---- fixed-base exp (raw v_exp_f32): masked -> exp2(-inf)=0
#pragma unroll
      for (int r = 0; r < 16; ++r) {
        st[0][r] = fexp2(st[0][r]);
        st[1][r] = fexp2(st[1][r]);
      }
      // ---- row-sum tree (compiler-emitted adds; consumes TRANS results)
      {
        float sm[8];
#pragma unroll
        for (int r = 0; r < 8; ++r)
          sm[r] = (st[0][r] + st[0][r + 8]) + (st[1][r] + st[1][r + 8]);
#pragma unroll
        for (int r = 0; r < 4; ++r) sm[r] += sm[r + 4];
        lsum += (sm[0] + sm[2]) + (sm[1] + sm[3]);
      }
    }

    if (pf) {  // write next tile into the other buffer (latency under PV)
      *reinterpret_cast<uint4*>(&Kt[cur ^ 1][srow][sc8]) = nK0;
      *reinterpret_cast<uint4*>(&Kt[cur ^ 1][srow + 32][sc8]) = nK1;
      *reinterpret_cast<uint4*>(&Vt[cur ^ 1][srow][sc8]) = nV0;
      *reinterpret_cast<uint4*>(&Vt[cur ^ 1][srow + 32][sc8]) = nV1;
    }

    if (active) {
      // ---- pack P to bf16 (compiler casts), permlane half-swap, PV
#pragma unroll
      for (int b = 0; b < 2; ++b) {
#pragma unroll
        for (int h = 0; h < 2; ++h) {  // kv 16-chunk c = 2b + h
          u32 a0 = pk2(st[b][h * 8 + 0], st[b][h * 8 + 1]);
          u32 a1 = pk2(st[b][h * 8 + 2], st[b][h * 8 + 3]);
          u32 a2 = pk2(st[b][h * 8 + 4], st[b][h * 8 + 5]);
          u32 a3 = pk2(st[b][h * 8 + 6], st[b][h * 8 + 7]);
          pl32swap(a0, a2);  // distinct values -> distinct regs
          pl32swap(a1, a3);
          union { u32 w[4]; bf16x8 v; } pb;
          pb.w[0] = a0; pb.w[1] = a1; pb.w[2] = a2; pb.w[3] = a3;
          const int c = 2 * b + h;
          __builtin_amdgcn_s_setprio(1);
#pragma unroll
          for (int db = 0; db < 2; ++db) {
            bf16x8 vf = ldb8(&Vt[cur][db * 32 + l32][c * 16 + hi * 8]);
            oacc[db] = mfma32(vf, pb.v, oacc[db]);
          }
          __builtin_amdgcn_s_setprio(0);
        }
      }
    }
    cur ^= 1;
  }

  // ---- combine partner halves of l, normalize, store O[q][d] bf16
  const float ltot = lsum + __shfl_xor(lsum, 32);
  const float linv = 1.f / ltot;

  u16* Op = Og + ((size_t)bb * SEQ + qlane) * DM + hh * HD;
#pragma unroll
  for (int db = 0; db < 2; ++db)
#pragma unroll
    for (int r = 0; r < 16; r += 2) {
      const int d = db * 32 + (r & 3) + 8 * (r >> 2) + 4 * hi;
      u32 pk = cvtpk(oacc[db][r] * linv, oacc[db][r + 1] * linv);
      *reinterpret_cast<u32*>(Op + d) = pk;
    }
}

// ---------------------------------------------------------------- launcher
extern "C" void kernel_launch(void* const* d_in, const int* in_sizes, int n_in,
                              void* d_out, int out_size, void* d_ws,
                              size_t ws_size, hipStream_t stream) {
  const float* x  = (const float*)d_in[0];
  const float* Wq = (const float*)d_in[1];
  const float* bq = (const float*)d_in[2];
  const float* Wk = (const float*)d_in[3];
  const float* bk = (const float*)d_in[4];
  const float* Wv = (const float*)d_in[5];
  const float* bv = (const float*)d_in[6];
  const float* Wo = (const float*)d_in[7];
  const float* bo = (const float*)d_in[8];
  float* out = (float*)d_out;

  u16* xb   = (u16*)d_ws;                       // [8192][768] bf16
  u16* Wall = xb + (size_t)MR * DM;             // 4 x [768][768] bf16
  u16* QKV  = Wall + (size_t)4 * DM * DM;       // Q,K: [bh][s][64]; V: [bh][d][s]
  u16* PRE  = QKV + (size_t)3 * MR * DM;        // [8192][768] bf16

  cvt_kernel<<<dim3(MR * DM / 8 / 256), 256, 0, stream>>>(x, xb, MR * DM / 8);
  cvt_w_kernel<<<dim3(DM * DM / 8 / 256, 4), 256, 0, stream>>>(Wq, Wk, Wv, Wo,
                                                               Wall);
  gemm_qkv_kernel<<<dim3(MR / 128, DM / 128, 3), 256, 0, stream>>>(
      xb, Wall, bq, bk, bv, QKV);
  attn_kernel<<<dim3(768), 256, 0, stream>>>(
      QKV, QKV + (size_t)MR * DM, QKV + (size_t)2 * MR * DM, PRE);
  gemm_out_kernel<<<dim3(MR / 128, DM / 128), 256, 0, stream>>>(
      PRE, Wall + (size_t)3 * DM * DM, bo, out);
}

// Round 12
// 173.158 us; speedup vs baseline: 1.8050x; 1.0052x over previous
//
#include <hip/hip_runtime.h>

typedef unsigned short u16;
typedef unsigned int u32;
typedef __bf16 bf16_t;
typedef bf16_t bf16x8 __attribute__((ext_vector_type(8)));
typedef float f32x4 __attribute__((ext_vector_type(4)));
typedef float f32x16 __attribute__((ext_vector_type(16)));

#define DM 768
#define HD 64
#define NH 12
#define NB 2
#define SEQ 4096
#define MR (NB * SEQ)  // 8192

#define SCL2E_F (0.125f * 1.44269504088896340736f)  // 1/sqrt(64) * log2(e)

__device__ __forceinline__ u16 f2bf(float f) {
  union { float f; u32 u; } v;
  v.f = f;
  u32 r = v.u + 0x7FFFu + ((v.u >> 16) & 1u);  // RNE, finite inputs only
  return (u16)(r >> 16);
}

// raw v_exp_f32 (no OCML denormal fixup). All consumers of its result MUST be
// compiler-emitted instructions (not inline asm) -- round-10 fail mode.
__device__ __forceinline__ float fexp2(float x) {
  return __builtin_amdgcn_exp2f(x);
}

// pack two f32 -> 2xbf16 in one u32 via compiler-emitted converts (m240:
// faster than hand-written v_cvt_pk asm, and hazard-safe after TRANS ops)
__device__ __forceinline__ u32 pk2(float a, float b) {
  union { bf16_t h[2]; u32 u; } x;
  x.h[0] = (bf16_t)a;
  x.h[1] = (bf16_t)b;
  return x.u;
}

// hardware pack for non-TRANS inputs (epilogue only)
__device__ __forceinline__ u32 cvtpk(float a, float b) {
  u32 r;
  asm("v_cvt_pk_bf16_f32 %0, %1, %2" : "=v"(r) : "v"(a), "v"(b));
  return r;
}

// half-swap between two DISTINCT registers (never call with identical values):
// a_new = lanes<32 ? a : b[lane-32];  b_new = lanes<32 ? a[lane+32] : b
__device__ __forceinline__ void pl32swap(u32& a, u32& b) {
  asm volatile("v_permlane32_swap_b32 %0, %1" : "+v"(a), "+v"(b));
}

__device__ __forceinline__ bf16x8 ldb8(const u16* p) {
  return *reinterpret_cast<const bf16x8*>(p);
}

__device__ __forceinline__ f32x4 mfma16(bf16x8 a, bf16x8 b, f32x4 c) {
  return __builtin_amdgcn_mfma_f32_16x16x32_bf16(a, b, c, 0, 0, 0);
}

__device__ __forceinline__ f32x16 mfma32(bf16x8 a, bf16x8 b, f32x16 c) {
  return __builtin_amdgcn_mfma_f32_32x32x16_bf16(a, b, c, 0, 0, 0);
}

#define GLDS16(g, l)                                              \
  __builtin_amdgcn_global_load_lds(                               \
      (const __attribute__((address_space(1))) void*)(g),         \
      (__attribute__((address_space(3))) void*)(l), 16, 0, 0)

// ---------------------------------------------------------------- converts
__global__ __launch_bounds__(256) void cvt_kernel(const float* __restrict__ src,
                                                  u16* __restrict__ dst, int n8) {
  int i = blockIdx.x * 256 + threadIdx.x;
  if (i >= n8) return;
  const float4* s = reinterpret_cast<const float4*>(src) + (size_t)i * 2;
  float4 a = s[0], b = s[1];
  union { u16 u[8]; uint4 v; } o;
  o.u[0] = f2bf(a.x); o.u[1] = f2bf(a.y); o.u[2] = f2bf(a.z); o.u[3] = f2bf(a.w);
  o.u[4] = f2bf(b.x); o.u[5] = f2bf(b.y); o.u[6] = f2bf(b.z); o.u[7] = f2bf(b.w);
  reinterpret_cast<uint4*>(dst)[i] = o.v;
}

__global__ __launch_bounds__(256) void cvt_w_kernel(const float* __restrict__ w0,
                                                    const float* __restrict__ w1,
                                                    const float* __restrict__ w2,
                                                    const float* __restrict__ w3,
                                                    u16* __restrict__ dst) {
  const float* src = (blockIdx.y == 0) ? w0 : (blockIdx.y == 1) ? w1
                   : (blockIdx.y == 2) ? w2 : w3;
  u16* d = dst + (size_t)blockIdx.y * DM * DM;
  int i = blockIdx.x * 256 + threadIdx.x;
  const float4* s = reinterpret_cast<const float4*>(src) + (size_t)i * 2;
  float4 a = s[0], b = s[1];
  union { u16 u[8]; uint4 v; } o;
  o.u[0] = f2bf(a.x); o.u[1] = f2bf(a.y); o.u[2] = f2bf(a.z); o.u[3] = f2bf(a.w);
  o.u[4] = f2bf(b.x); o.u[5] = f2bf(b.y); o.u[6] = f2bf(b.z); o.u[7] = f2bf(b.w);
  reinterpret_cast<uint4*>(d)[i] = o.v;
}

// ---------------------------------------------------------------- QKV GEMM
// C[m,n] = sum_k A[m,k] * W[n,k] + bias[n]
// z==0 (Q): scaled by SCL2E, layout [bh][s][64]
// z==1 (K): layout [bh][s][64]
// z==2 (V): TRANSPOSED layout [bh][d][s]  (V^T, packed uint2 stores)
__global__ __launch_bounds__(256) void gemm_qkv_kernel(
    const u16* __restrict__ A, const u16* __restrict__ Wall,
    const float* __restrict__ b0, const float* __restrict__ b1,
    const float* __restrict__ b2, u16* __restrict__ O) {
  __shared__ __align__(16) u16 As[128 * 32];
  __shared__ __align__(16) u16 Bs[128 * 32];

  const int tid = threadIdx.x;
  const int w = tid >> 6, lane = tid & 63;
  const int l16 = lane & 15, lg = lane >> 4;
  const int wm = w >> 1, wn = w & 1;

  const int m0 = blockIdx.x * 128;
  const int n0 = blockIdx.y * 128;
  const int z = blockIdx.z;

  const u16* W = Wall + (size_t)z * DM * DM;
  const float* bias = (z == 0) ? b0 : ((z == 1) ? b1 : b2);
  u16* oz = O + (size_t)z * MR * DM;
  const float qscale = (z == 0) ? SCL2E_F : 1.f;

  f32x4 acc[4][4];
#pragma unroll
  for (int i = 0; i < 4; ++i)
#pragma unroll
    for (int j = 0; j < 4; ++j) {
      acc[i][j][0] = 0.f; acc[i][j][1] = 0.f;
      acc[i][j][2] = 0.f; acc[i][j][3] = 0.f;
    }

  for (int k0 = 0; k0 < DM; k0 += 32) {
#pragma unroll
    for (int i = 0; i < 2; ++i) {
      const int c = (w * 2 + i) * 64 + lane;
      const int m = c >> 2, kc = c & 3;
      GLDS16(A + (size_t)(m0 + m) * DM + (k0 + kc * 8),
             As + (size_t)(w * 2 + i) * 512);
      GLDS16(W + (size_t)(n0 + m) * DM + (k0 + kc * 8),
             Bs + (size_t)(w * 2 + i) * 512);
    }
    __syncthreads();
    bf16x8 af[4], bfv[4];
#pragma unroll
    for (int i = 0; i < 4; ++i)
      af[i] = ldb8(As + (wm * 64 + i * 16 + l16) * 32 + lg * 8);
#pragma unroll
    for (int j = 0; j < 4; ++j)
      bfv[j] = ldb8(Bs + (wn * 64 + j * 16 + l16) * 32 + lg * 8);
#pragma unroll
    for (int i = 0; i < 4; ++i)
#pragma unroll
      for (int j = 0; j < 4; ++j)
        acc[i][j] = mfma16(af[i], bfv[j], acc[i][j]);
    __syncthreads();
  }

#pragma unroll
  for (int i = 0; i < 4; ++i) {
    const int gm = m0 + wm * 64 + i * 16 + lg * 4;
    const int bb = gm >> 12;          // /SEQ
    const int ss = gm & (SEQ - 1);
#pragma unroll
    for (int j = 0; j < 4; ++j) {
      const int gn = n0 + wn * 64 + j * 16 + l16;
      const int hh = gn >> 6, dd = gn & (HD - 1);
      const float bv = bias[gn];
      if (z == 2) {
        union { u16 u[4]; uint2 v; } pk;
#pragma unroll
        for (int r = 0; r < 4; ++r) pk.u[r] = f2bf(acc[i][j][r] + bv);
        *reinterpret_cast<uint2*>(
            oz + ((size_t)(bb * NH + hh) * HD + dd) * SEQ + ss) = pk.v;
      } else {
        u16* op = oz + ((size_t)(bb * NH + hh) * SEQ + ss) * HD + dd;
#pragma unroll
        for (int r = 0; r < 4; ++r)
          op[(size_t)r * HD] = f2bf((acc[i][j][r] + bv) * qscale);
      }
    }
  }
}

// ---------------------------------------------------------------- out proj
__global__ __launch_bounds__(256) void gemm_out_kernel(
    const u16* __restrict__ A, const u16* __restrict__ W,
    const float* __restrict__ bias, float* __restrict__ Out) {
  __shared__ __align__(16) u16 As[128 * 32];
  __shared__ __align__(16) u16 Bs[128 * 32];

  const int tid = threadIdx.x;
  const int w = tid >> 6, lane = tid & 63;
  const int l16 = lane & 15, lg = lane >> 4;
  const int wm = w >> 1, wn = w & 1;

  const int m0 = blockIdx.x * 128;
  const int n0 = blockIdx.y * 128;

  f32x4 acc[4][4];
#pragma unroll
  for (int i = 0; i < 4; ++i)
#pragma unroll
    for (int j = 0; j < 4; ++j) {
      acc[i][j][0] = 0.f; acc[i][j][1] = 0.f;
      acc[i][j][2] = 0.f; acc[i][j][3] = 0.f;
    }

  for (int k0 = 0; k0 < DM; k0 += 32) {
#pragma unroll
    for (int i = 0; i < 2; ++i) {
      const int c = (w * 2 + i) * 64 + lane;
      const int m = c >> 2, kc = c & 3;
      GLDS16(A + (size_t)(m0 + m) * DM + (k0 + kc * 8),
             As + (size_t)(w * 2 + i) * 512);
      GLDS16(W + (size_t)(n0 + m) * DM + (k0 + kc * 8),
             Bs + (size_t)(w * 2 + i) * 512);
    }
    __syncthreads();
    bf16x8 af[4], bfv[4];
#pragma unroll
    for (int i = 0; i < 4; ++i)
      af[i] = ldb8(As + (wm * 64 + i * 16 + l16) * 32 + lg * 8);
#pragma unroll
    for (int j = 0; j < 4; ++j)
      bfv[j] = ldb8(Bs + (wn * 64 + j * 16 + l16) * 32 + lg * 8);
#pragma unroll
    for (int i = 0; i < 4; ++i)
#pragma unroll
      for (int j = 0; j < 4; ++j)
        acc[i][j] = mfma16(af[i], bfv[j], acc[i][j]);
    __syncthreads();
  }

#pragma unroll
  for (int i = 0; i < 4; ++i) {
    const int gm = m0 + wm * 64 + i * 16 + lg * 4;
#pragma unroll
    for (int j = 0; j < 4; ++j) {
      const int gn = n0 + wn * 64 + j * 16 + l16;
      const float bv = bias[gn];
      float* op = Out + (size_t)gm * DM + gn;
#pragma unroll
      for (int r = 0; r < 4; ++r)
        op[(size_t)r * DM] = acc[i][j][r] + bv;
    }
  }
}

// ---------------------------------------------------------------- attention
// 1-D grid of 768 blocks, longest-first: qt = 31 - idx/24, bh = idx%24.
// 4 waves x 32 q-rows, KV tile 64, double-buffered K/V LDS, 1 barrier/tile.
// Swapped QK^T (32x32x16): lane holds S^T[kv=crow(reg,hi)][q=lane&31].
// FIXED-BASE softmax with raw v_exp_f32; exp results consumed only by
// compiler-emitted instructions. QK chain seeded with loop-invariant zero16
// (removes 32 per-tile acc zero-init movs).
__global__ __launch_bounds__(256) void attn_kernel(
    const u16* __restrict__ Qg, const u16* __restrict__ Kg,
    const u16* __restrict__ VTg, u16* __restrict__ Og) {
  __shared__ __align__(16) u16 Kt[2][64][72];   // [buf][kv][d], +8 pad
  __shared__ __align__(16) u16 Vt[2][64][72];   // [buf][d][kv], +8 pad (V^T)

  const int tid = threadIdx.x;
  const int w = tid >> 6, lane = tid & 63;
  const int l32 = lane & 31, hi = lane >> 5;

  const int idx = blockIdx.x;            // 0..767
  const int qt = 31 - (idx / 24);        // longest blocks dispatch first
  const int bh = idx % 24;
  const int bb = bh / NH, hh = bh % NH;

  const u16* Qp = Qg + (size_t)bh * SEQ * HD;
  const u16* Kp = Kg + (size_t)bh * SEQ * HD;
  const u16* VTp = VTg + (size_t)bh * HD * SEQ;

  const int qw0 = qt * 128 + w * 32;
  const int qlane = qw0 + l32;

  // Q fragments (B-operand): qf[c][j] = Q[q][c*16 + hi*8 + j]  (pre-scaled)
  bf16x8 qf[4];
#pragma unroll
  for (int c = 0; c < 4; ++c)
    qf[c] = ldb8(Qp + (size_t)qlane * HD + c * 16 + hi * 8);

  f32x16 oacc[2];  // O^T[32*db + crow(reg,hi)][q=l32]
  f32x16 zero16;   // loop-invariant MFMA C-seed (C is read-only, D != C ok)
#pragma unroll
  for (int r = 0; r < 16; ++r) zero16[r] = 0.f;
#pragma unroll
  for (int db = 0; db < 2; ++db)
#pragma unroll
    for (int r = 0; r < 16; ++r) oacc[db][r] = 0.f;
  float lsum = 0.f;

  // staging coords: 8 threads per 64-elem row, rows srow and srow+32
  const int srow = tid >> 3;        // 0..31
  const int sc8 = (tid & 7) * 8;

  // running staging pointers (strength-reduced; advance by constant stride)
  const u16* kP0 = Kp + (size_t)srow * HD + sc8;
  const u16* kP1 = kP0 + (size_t)32 * HD;
  const u16* vP0 = VTp + (size_t)srow * SEQ + sc8;
  const u16* vP1 = vP0 + (size_t)32 * SEQ;

  // ---- prologue: stage tile 0 into buffer 0
  {
    uint4 a = *reinterpret_cast<const uint4*>(kP0);
    uint4 b = *reinterpret_cast<const uint4*>(kP1);
    uint4 c = *reinterpret_cast<const uint4*>(vP0);
    uint4 d = *reinterpret_cast<const uint4*>(vP1);
    *reinterpret_cast<uint4*>(&Kt[0][srow][sc8]) = a;
    *reinterpret_cast<uint4*>(&Kt[0][srow + 32][sc8]) = b;
    *reinterpret_cast<uint4*>(&Vt[0][srow][sc8]) = c;
    *reinterpret_cast<uint4*>(&Vt[0][srow + 32][sc8]) = d;
  }
  kP0 += (size_t)64 * HD; kP1 += (size_t)64 * HD;
  vP0 += 64; vP1 += 64;

  const int NT = 2 * qt + 2;
  int cur = 0;
  for (int t = 0; t < NT; ++t) {
    const int kv0 = t * 64;
    const bool pf = (t + 1 < NT);
    uint4 nK0, nK1, nV0, nV1;
    if (pf) {  // prefetch next tile to regs (latency spans barrier + QK)
      nK0 = *reinterpret_cast<const uint4*>(kP0);
      nK1 = *reinterpret_cast<const uint4*>(kP1);
      nV0 = *reinterpret_cast<const uint4*>(vP0);
      nV1 = *reinterpret_cast<const uint4*>(vP1);
    }
    kP0 += (size_t)64 * HD; kP1 += (size_t)64 * HD;
    vP0 += 64; vP1 += 64;
    __syncthreads();  // buf[cur] writes visible; prev reads of buf[cur^1] done

    const bool active = (kv0 <= qw0 + 31);
    f32x16 st[2];
    if (active) {
      // ---- QK^T (swapped): st[b] = S^T[kv=32b+crow][q], C seeded by zero16
      __builtin_amdgcn_s_setprio(1);
#pragma unroll
      for (int b = 0; b < 2; ++b) {
        {
          bf16x8 kf = ldb8(&Kt[cur][b * 32 + l32][hi * 8]);
          st[b] = mfma32(kf, qf[0], zero16);
        }
#pragma unroll
        for (int c = 1; c < 4; ++c) {
          bf16x8 kf = ldb8(&Kt[cur][b * 32 + l32][c * 16 + hi * 8]);
          st[b] = mfma32(kf, qf[c], st[b]);
        }
      }
      __builtin_amdgcn_s_setprio(0);

      // ---- causal mask (diagonal tiles only)
      if (kv0 + 63 > qw0) {
#pragma unroll
        for (int b = 0; b < 2; ++b)
#pragma unroll
          for (int r = 0; r < 16; ++r) {
            const int kvi = kv0 + b * 32 + (r & 3) + 8 * (r >> 2) + 4 * hi;
            if (kvi > qlane) st[b][r] = -__builtin_inff();
          }
      }

      // ---- fixed-base exp (raw v_exp_f32): masked -> exp2(-inf)=0
#pragma unroll
      for (int r = 0; r < 16; ++r) {
        st[0][r] = fexp2(st[0][r]);
        st[1][r] = fexp2(st[1][r]);
      }
      // ---- row-sum tree (compiler-emitted adds; consumes TRANS results)
      {
        float sm[8];
#pragma unroll
        for (int r = 0; r < 8; ++r)
          sm[r] = (st[0][r] + st[0][r + 8]) + (st[1][r] + st[1][r + 8]);
#pragma unroll
        for (int r = 0; r < 4; ++r) sm[r] += sm[r + 4];
        lsum += (sm[0] + sm[2]) + (sm[1] + sm[3]);
      }
    }

    if (pf) {  // write next tile into the other buffer (latency under PV)
      *reinterpret_cast<uint4*>(&Kt[cur ^ 1][srow][sc8]) = nK0;
      *reinterpret_cast<uint4*>(&Kt[cur ^ 1][srow + 32][sc8]) = nK1;
      *reinterpret_cast<uint4*>(&Vt[cur ^ 1][srow][sc8]) = nV0;
      *reinterpret_cast<uint4*>(&Vt[cur ^ 1][srow + 32][sc8]) = nV1;
    }

    if (active) {
      // ---- pack P to bf16 (compiler casts), permlane half-swap, PV
#pragma unroll
      for (int b = 0; b < 2; ++b) {
#pragma unroll
        for (int h = 0; h < 2; ++h) {  // kv 16-chunk c = 2b + h
          u32 a0 = pk2(st[b][h * 8 + 0], st[b][h * 8 + 1]);
          u32 a1 = pk2(st[b][h * 8 + 2], st[b][h * 8 + 3]);
          u32 a2 = pk2(st[b][h * 8 + 4], st[b][h * 8 + 5]);
          u32 a3 = pk2(st[b][h * 8 + 6], st[b][h * 8 + 7]);
          pl32swap(a0, a2);  // distinct values -> distinct regs
          pl32swap(a1, a3);
          union { u32 w[4]; bf16x8 v; } pb;
          pb.w[0] = a0; pb.w[1] = a1; pb.w[2] = a2; pb.w[3] = a3;
          const int c = 2 * b + h;
          __builtin_amdgcn_s_setprio(1);
#pragma unroll
          for (int db = 0; db < 2; ++db) {
            bf16x8 vf = ldb8(&Vt[cur][db * 32 + l32][c * 16 + hi * 8]);
            oacc[db] = mfma32(vf, pb.v, oacc[db]);
          }
          __builtin_amdgcn_s_setprio(0);
        }
      }
    }
    cur ^= 1;
  }

  // ---- combine partner halves of l, normalize, store O[q][d] bf16
  const float ltot = lsum + __shfl_xor(lsum, 32);
  const float linv = 1.f / ltot;

  u16* Op = Og + ((size_t)bb * SEQ + qlane) * DM + hh * HD;
#pragma unroll
  for (int db = 0; db < 2; ++db)
#pragma unroll
    for (int r = 0; r < 16; r += 2) {
      const int d = db * 32 + (r & 3) + 8 * (r >> 2) + 4 * hi;
      u32 pk = cvtpk(oacc[db][r] * linv, oacc[db][r + 1] * linv);
      *reinterpret_cast<u32*>(Op + d) = pk;
    }
}

// ---------------------------------------------------------------- launcher
extern "C" void kernel_launch(void* const* d_in, const int* in_sizes, int n_in,
                              void* d_out, int out_size, void* d_ws,
                              size_t ws_size, hipStream_t stream) {
  const float* x  = (const float*)d_in[0];
  const float* Wq = (const float*)d_in[1];
  const float* bq = (const float*)d_in[2];
  const float* Wk = (const float*)d_in[3];
  const float* bk = (const float*)d_in[4];
  const float* Wv = (const float*)d_in[5];
  const float* bv = (const float*)d_in[6];
  const float* Wo = (const float*)d_in[7];
  const float* bo = (const float*)d_in[8];
  float* out = (float*)d_out;

  u16* xb   = (u16*)d_ws;                       // [8192][768] bf16
  u16* Wall = xb + (size_t)MR * DM;             // 4 x [768][768] bf16
  u16* QKV  = Wall + (size_t)4 * DM * DM;       // Q,K: [bh][s][64]; V: [bh][d][s]
  u16* PRE  = QKV + (size_t)3 * MR * DM;        // [8192][768] bf16

  cvt_kernel<<<dim3(MR * DM / 8 / 256), 256, 0, stream>>>(x, xb, MR * DM / 8);
  cvt_w_kernel<<<dim3(DM * DM / 8 / 256, 4), 256, 0, stream>>>(Wq, Wk, Wv, Wo,
                                                               Wall);
  gemm_qkv_kernel<<<dim3(MR / 128, DM / 128, 3), 256, 0, stream>>>(
      xb, Wall, bq, bk, bv, QKV);
  attn_kernel<<<dim3(768), 256, 0, stream>>>(
      QKV, QKV + (size_t)MR * DM, QKV + (size_t)2 * MR * DM, PRE);
  gemm_out_kernel<<<dim3(MR / 128, DM / 128), 256, 0, stream>>>(
      PRE, Wall + (size_t)3 * DM * DM, bo, out);
}

// Round 13
// 172.858 us; speedup vs baseline: 1.8082x; 1.0017x over previous
//
#include <hip/hip_runtime.h>

typedef unsigned short u16;
typedef unsigned int u32;
typedef __bf16 bf16_t;
typedef bf16_t bf16x8 __attribute__((ext_vector_type(8)));
typedef float f32x4 __attribute__((ext_vector_type(4)));
typedef float f32x16 __attribute__((ext_vector_type(16)));

#define DM 768
#define HD 64
#define NH 12
#define NB 2
#define SEQ 4096
#define MR (NB * SEQ)  // 8192

#define SCL2E_F (0.125f * 1.44269504088896340736f)  // 1/sqrt(64) * log2(e)

__device__ __forceinline__ u16 f2bf(float f) {
  union { float f; u32 u; } v;
  v.f = f;
  u32 r = v.u + 0x7FFFu + ((v.u >> 16) & 1u);  // RNE, finite inputs only
  return (u16)(r >> 16);
}

// raw v_exp_f32 (no OCML denormal fixup). All consumers of its result MUST be
// compiler-emitted instructions (not inline asm) -- round-10 fail mode.
__device__ __forceinline__ float fexp2(float x) {
  return __builtin_amdgcn_exp2f(x);
}

// pack two f32 -> 2xbf16 in one u32 via compiler-emitted converts (m240:
// faster than hand-written v_cvt_pk asm, and hazard-safe after TRANS ops)
__device__ __forceinline__ u32 pk2(float a, float b) {
  union { bf16_t h[2]; u32 u; } x;
  x.h[0] = (bf16_t)a;
  x.h[1] = (bf16_t)b;
  return x.u;
}

// hardware pack for non-TRANS inputs (epilogue only)
__device__ __forceinline__ u32 cvtpk(float a, float b) {
  u32 r;
  asm("v_cvt_pk_bf16_f32 %0, %1, %2" : "=v"(r) : "v"(a), "v"(b));
  return r;
}

// half-swap between two DISTINCT registers (never call with identical values):
// a_new = lanes<32 ? a : b[lane-32];  b_new = lanes<32 ? a[lane+32] : b
__device__ __forceinline__ void pl32swap(u32& a, u32& b) {
  asm volatile("v_permlane32_swap_b32 %0, %1" : "+v"(a), "+v"(b));
}

__device__ __forceinline__ bf16x8 ldb8(const u16* p) {
  return *reinterpret_cast<const bf16x8*>(p);
}

__device__ __forceinline__ f32x4 mfma16(bf16x8 a, bf16x8 b, f32x4 c) {
  return __builtin_amdgcn_mfma_f32_16x16x32_bf16(a, b, c, 0, 0, 0);
}

__device__ __forceinline__ f32x16 mfma32(bf16x8 a, bf16x8 b, f32x16 c) {
  return __builtin_amdgcn_mfma_f32_32x32x16_bf16(a, b, c, 0, 0, 0);
}

#define GLDS16(g, l)                                              \
  __builtin_amdgcn_global_load_lds(                               \
      (const __attribute__((address_space(1))) void*)(g),         \
      (__attribute__((address_space(3))) void*)(l), 16, 0, 0)

// ---------------------------------------------------------------- converts
__global__ __launch_bounds__(256) void cvt_kernel(const float* __restrict__ src,
                                                  u16* __restrict__ dst, int n8) {
  int i = blockIdx.x * 256 + threadIdx.x;
  if (i >= n8) return;
  const float4* s = reinterpret_cast<const float4*>(src) + (size_t)i * 2;
  float4 a = s[0], b = s[1];
  union { u16 u[8]; uint4 v; } o;
  o.u[0] = f2bf(a.x); o.u[1] = f2bf(a.y); o.u[2] = f2bf(a.z); o.u[3] = f2bf(a.w);
  o.u[4] = f2bf(b.x); o.u[5] = f2bf(b.y); o.u[6] = f2bf(b.z); o.u[7] = f2bf(b.w);
  reinterpret_cast<uint4*>(dst)[i] = o.v;
}

__global__ __launch_bounds__(256) void cvt_w_kernel(const float* __restrict__ w0,
                                                    const float* __restrict__ w1,
                                                    const float* __restrict__ w2,
                                                    const float* __restrict__ w3,
                                                    u16* __restrict__ dst) {
  const float* src = (blockIdx.y == 0) ? w0 : (blockIdx.y == 1) ? w1
                   : (blockIdx.y == 2) ? w2 : w3;
  u16* d = dst + (size_t)blockIdx.y * DM * DM;
  int i = blockIdx.x * 256 + threadIdx.x;
  const float4* s = reinterpret_cast<const float4*>(src) + (size_t)i * 2;
  float4 a = s[0], b = s[1];
  union { u16 u[8]; uint4 v; } o;
  o.u[0] = f2bf(a.x); o.u[1] = f2bf(a.y); o.u[2] = f2bf(a.z); o.u[3] = f2bf(a.w);
  o.u[4] = f2bf(b.x); o.u[5] = f2bf(b.y); o.u[6] = f2bf(b.z); o.u[7] = f2bf(b.w);
  reinterpret_cast<uint4*>(d)[i] = o.v;
}

// ---------------------------------------------------------------- QKV GEMM
// C[m,n] = sum_k A[m,k] * W[n,k] + bias[n]
// z==0 (Q): scaled by SCL2E, layout [bh][s][64]
// z==1 (K): layout [bh][s][64]
// z==2 (V): TRANSPOSED layout [bh][d][s]  (V^T, packed uint2 stores)
__global__ __launch_bounds__(256) void gemm_qkv_kernel(
    const u16* __restrict__ A, const u16* __restrict__ Wall,
    const float* __restrict__ b0, const float* __restrict__ b1,
    const float* __restrict__ b2, u16* __restrict__ O) {
  __shared__ __align__(16) u16 As[128 * 32];
  __shared__ __align__(16) u16 Bs[128 * 32];

  const int tid = threadIdx.x;
  const int w = tid >> 6, lane = tid & 63;
  const int l16 = lane & 15, lg = lane >> 4;
  const int wm = w >> 1, wn = w & 1;

  const int m0 = blockIdx.x * 128;
  const int n0 = blockIdx.y * 128;
  const int z = blockIdx.z;

  const u16* W = Wall + (size_t)z * DM * DM;
  const float* bias = (z == 0) ? b0 : ((z == 1) ? b1 : b2);
  u16* oz = O + (size_t)z * MR * DM;
  const float qscale = (z == 0) ? SCL2E_F : 1.f;

  f32x4 acc[4][4];
#pragma unroll
  for (int i = 0; i < 4; ++i)
#pragma unroll
    for (int j = 0; j < 4; ++j) {
      acc[i][j][0] = 0.f; acc[i][j][1] = 0.f;
      acc[i][j][2] = 0.f; acc[i][j][3] = 0.f;
    }

  for (int k0 = 0; k0 < DM; k0 += 32) {
#pragma unroll
    for (int i = 0; i < 2; ++i) {
      const int c = (w * 2 + i) * 64 + lane;
      const int m = c >> 2, kc = c & 3;
      GLDS16(A + (size_t)(m0 + m) * DM + (k0 + kc * 8),
             As + (size_t)(w * 2 + i) * 512);
      GLDS16(W + (size_t)(n0 + m) * DM + (k0 + kc * 8),
             Bs + (size_t)(w * 2 + i) * 512);
    }
    __syncthreads();
    bf16x8 af[4], bfv[4];
#pragma unroll
    for (int i = 0; i < 4; ++i)
      af[i] = ldb8(As + (wm * 64 + i * 16 + l16) * 32 + lg * 8);
#pragma unroll
    for (int j = 0; j < 4; ++j)
      bfv[j] = ldb8(Bs + (wn * 64 + j * 16 + l16) * 32 + lg * 8);
#pragma unroll
    for (int i = 0; i < 4; ++i)
#pragma unroll
      for (int j = 0; j < 4; ++j)
        acc[i][j] = mfma16(af[i], bfv[j], acc[i][j]);
    __syncthreads();
  }

#pragma unroll
  for (int i = 0; i < 4; ++i) {
    const int gm = m0 + wm * 64 + i * 16 + lg * 4;
    const int bb = gm >> 12;          // /SEQ
    const int ss = gm & (SEQ - 1);
#pragma unroll
    for (int j = 0; j < 4; ++j) {
      const int gn = n0 + wn * 64 + j * 16 + l16;
      const int hh = gn >> 6, dd = gn & (HD - 1);
      const float bv = bias[gn];
      if (z == 2) {
        union { u16 u[4]; uint2 v; } pk;
#pragma unroll
        for (int r = 0; r < 4; ++r) pk.u[r] = f2bf(acc[i][j][r] + bv);
        *reinterpret_cast<uint2*>(
            oz + ((size_t)(bb * NH + hh) * HD + dd) * SEQ + ss) = pk.v;
      } else {
        u16* op = oz + ((size_t)(bb * NH + hh) * SEQ + ss) * HD + dd;
#pragma unroll
        for (int r = 0; r < 4; ++r)
          op[(size_t)r * HD] = f2bf((acc[i][j][r] + bv) * qscale);
      }
    }
  }
}

// ---------------------------------------------------------------- out proj
__global__ __launch_bounds__(256) void gemm_out_kernel(
    const u16* __restrict__ A, const u16* __restrict__ W,
    const float* __restrict__ bias, float* __restrict__ Out) {
  __shared__ __align__(16) u16 As[128 * 32];
  __shared__ __align__(16) u16 Bs[128 * 32];

  const int tid = threadIdx.x;
  const int w = tid >> 6, lane = tid & 63;
  const int l16 = lane & 15, lg = lane >> 4;
  const int wm = w >> 1, wn = w & 1;

  const int m0 = blockIdx.x * 128;
  const int n0 = blockIdx.y * 128;

  f32x4 acc[4][4];
#pragma unroll
  for (int i = 0; i < 4; ++i)
#pragma unroll
    for (int j = 0; j < 4; ++j) {
      acc[i][j][0] = 0.f; acc[i][j][1] = 0.f;
      acc[i][j][2] = 0.f; acc[i][j][3] = 0.f;
    }

  for (int k0 = 0; k0 < DM; k0 += 32) {
#pragma unroll
    for (int i = 0; i < 2; ++i) {
      const int c = (w * 2 + i) * 64 + lane;
      const int m = c >> 2, kc = c & 3;
      GLDS16(A + (size_t)(m0 + m) * DM + (k0 + kc * 8),
             As + (size_t)(w * 2 + i) * 512);
      GLDS16(W + (size_t)(n0 + m) * DM + (k0 + kc * 8),
             Bs + (size_t)(w * 2 + i) * 512);
    }
    __syncthreads();
    bf16x8 af[4], bfv[4];
#pragma unroll
    for (int i = 0; i < 4; ++i)
      af[i] = ldb8(As + (wm * 64 + i * 16 + l16) * 32 + lg * 8);
#pragma unroll
    for (int j = 0; j < 4; ++j)
      bfv[j] = ldb8(Bs + (wn * 64 + j * 16 + l16) * 32 + lg * 8);
#pragma unroll
    for (int i = 0; i < 4; ++i)
#pragma unroll
      for (int j = 0; j < 4; ++j)
        acc[i][j] = mfma16(af[i], bfv[j], acc[i][j]);
    __syncthreads();
  }

#pragma unroll
  for (int i = 0; i < 4; ++i) {
    const int gm = m0 + wm * 64 + i * 16 + lg * 4;
#pragma unroll
    for (int j = 0; j < 4; ++j) {
      const int gn = n0 + wn * 64 + j * 16 + l16;
      const float bv = bias[gn];
      float* op = Out + (size_t)gm * DM + gn;
#pragma unroll
      for (int r = 0; r < 4; ++r)
        op[(size_t)r * DM] = acc[i][j][r] + bv;
    }
  }
}

// ---------------------------------------------------------------- attention
// 1-D grid of 768 blocks, XCD-aware: idx%8 pins bh%8 (each XCD's L2 serves
// only 3 heads' K/V = 6 MB instead of 24 heads = 48 MB); longest-first
// within each XCD (qt descending). bh = (idx/8 % 3)*8 + idx%8;
// qt = 31 - idx/24. 4 waves x 32 q-rows, KV tile 64, double-buffered LDS.
// Swapped QK^T (32x32x16): lane holds S^T[kv=crow(reg,hi)][q=lane&31].
// FIXED-BASE softmax with raw v_exp_f32; exp results consumed only by
// compiler-emitted instructions. QK chain seeded with loop-invariant zero16.
__global__ __launch_bounds__(256) void attn_kernel(
    const u16* __restrict__ Qg, const u16* __restrict__ Kg,
    const u16* __restrict__ VTg, u16* __restrict__ Og) {
  __shared__ __align__(16) u16 Kt[2][64][72];   // [buf][kv][d], +8 pad
  __shared__ __align__(16) u16 Vt[2][64][72];   // [buf][d][kv], +8 pad (V^T)

  const int tid = threadIdx.x;
  const int w = tid >> 6, lane = tid & 63;
  const int l32 = lane & 31, hi = lane >> 5;

  const int idx = blockIdx.x;            // 0..767
  const int x8 = idx & 7;                // XCD residue
  const int g = idx >> 3;                // 0..95
  const int qt = 31 - g / 3;             // longest blocks dispatch first
  const int bh = (g % 3) * 8 + x8;       // bh%8 pinned to XCD
  const int bb = bh / NH, hh = bh % NH;

  const u16* Qp = Qg + (size_t)bh * SEQ * HD;
  const u16* Kp = Kg + (size_t)bh * SEQ * HD;
  const u16* VTp = VTg + (size_t)bh * HD * SEQ;

  const int qw0 = qt * 128 + w * 32;
  const int qlane = qw0 + l32;

  // Q fragments (B-operand): qf[c][j] = Q[q][c*16 + hi*8 + j]  (pre-scaled)
  bf16x8 qf[4];
#pragma unroll
  for (int c = 0; c < 4; ++c)
    qf[c] = ldb8(Qp + (size_t)qlane * HD + c * 16 + hi * 8);

  f32x16 oacc[2];  // O^T[32*db + crow(reg,hi)][q=l32]
  f32x16 zero16;   // loop-invariant MFMA C-seed (C is read-only, D != C ok)
#pragma unroll
  for (int r = 0; r < 16; ++r) zero16[r] = 0.f;
#pragma unroll
  for (int db = 0; db < 2; ++db)
#pragma unroll
    for (int r = 0; r < 16; ++r) oacc[db][r] = 0.f;
  float lsum = 0.f;

  // staging coords: 8 threads per 64-elem row, rows srow and srow+32
  const int srow = tid >> 3;        // 0..31
  const int sc8 = (tid & 7) * 8;

  // running staging pointers (strength-reduced; advance by constant stride)
  const u16* kP0 = Kp + (size_t)srow * HD + sc8;
  const u16* kP1 = kP0 + (size_t)32 * HD;
  const u16* vP0 = VTp + (size_t)srow * SEQ + sc8;
  const u16* vP1 = vP0 + (size_t)32 * SEQ;

  // ---- prologue: stage tile 0 into buffer 0
  {
    uint4 a = *reinterpret_cast<const uint4*>(kP0);
    uint4 b = *reinterpret_cast<const uint4*>(kP1);
    uint4 c = *reinterpret_cast<const uint4*>(vP0);
    uint4 d = *reinterpret_cast<const uint4*>(vP1);
    *reinterpret_cast<uint4*>(&Kt[0][srow][sc8]) = a;
    *reinterpret_cast<uint4*>(&Kt[0][srow + 32][sc8]) = b;
    *reinterpret_cast<uint4*>(&Vt[0][srow][sc8]) = c;
    *reinterpret_cast<uint4*>(&Vt[0][srow + 32][sc8]) = d;
  }
  kP0 += (size_t)64 * HD; kP1 += (size_t)64 * HD;
  vP0 += 64; vP1 += 64;

  const int NT = 2 * qt + 2;
  int cur = 0;
  for (int t = 0; t < NT; ++t) {
    const int kv0 = t * 64;
    const bool pf = (t + 1 < NT);
    uint4 nK0, nK1, nV0, nV1;
    if (pf) {  // prefetch next tile to regs (latency spans barrier + QK)
      nK0 = *reinterpret_cast<const uint4*>(kP0);
      nK1 = *reinterpret_cast<const uint4*>(kP1);
      nV0 = *reinterpret_cast<const uint4*>(vP0);
      nV1 = *reinterpret_cast<const uint4*>(vP1);
    }
    kP0 += (size_t)64 * HD; kP1 += (size_t)64 * HD;
    vP0 += 64; vP1 += 64;
    __syncthreads();  // buf[cur] writes visible; prev reads of buf[cur^1] done

    const bool active = (kv0 <= qw0 + 31);
    f32x16 st[2];
    if (active) {
      // ---- QK^T (swapped): st[b] = S^T[kv=32b+crow][q], C seeded by zero16
      __builtin_amdgcn_s_setprio(1);
#pragma unroll
      for (int b = 0; b < 2; ++b) {
        {
          bf16x8 kf = ldb8(&Kt[cur][b * 32 + l32][hi * 8]);
          st[b] = mfma32(kf, qf[0], zero16);
        }
#pragma unroll
        for (int c = 1; c < 4; ++c) {
          bf16x8 kf = ldb8(&Kt[cur][b * 32 + l32][c * 16 + hi * 8]);
          st[b] = mfma32(kf, qf[c], st[b]);
        }
      }
      __builtin_amdgcn_s_setprio(0);

      // ---- causal mask (diagonal tiles only)
      if (kv0 + 63 > qw0) {
#pragma unroll
        for (int b = 0; b < 2; ++b)
#pragma unroll
          for (int r = 0; r < 16; ++r) {
            const int kvi = kv0 + b * 32 + (r & 3) + 8 * (r >> 2) + 4 * hi;
            if (kvi > qlane) st[b][r] = -__builtin_inff();
          }
      }

      // ---- fixed-base exp (raw v_exp_f32): masked -> exp2(-inf)=0
#pragma unroll
      for (int r = 0; r < 16; ++r) {
        st[0][r] = fexp2(st[0][r]);
        st[1][r] = fexp2(st[1][r]);
      }
      // ---- row-sum tree (compiler-emitted adds; consumes TRANS results)
      {
        float sm[8];
#pragma unroll
        for (int r = 0; r < 8; ++r)
          sm[r] = (st[0][r] + st[0][r + 8]) + (st[1][r] + st[1][r + 8]);
#pragma unroll
        for (int r = 0; r < 4; ++r) sm[r] += sm[r + 4];
        lsum += (sm[0] + sm[2]) + (sm[1] + sm[3]);
      }
    }

    if (pf) {  // write next tile into the other buffer (latency under PV)
      *reinterpret_cast<uint4*>(&Kt[cur ^ 1][srow][sc8]) = nK0;
      *reinterpret_cast<uint4*>(&Kt[cur ^ 1][srow + 32][sc8]) = nK1;
      *reinterpret_cast<uint4*>(&Vt[cur ^ 1][srow][sc8]) = nV0;
      *reinterpret_cast<uint4*>(&Vt[cur ^ 1][srow + 32][sc8]) = nV1;
    }

    if (active) {
      // ---- pack P to bf16 (compiler casts), permlane half-swap, PV
#pragma unroll
      for (int b = 0; b < 2; ++b) {
#pragma unroll
        for (int h = 0; h < 2; ++h) {  // kv 16-chunk c = 2b + h
          u32 a0 = pk2(st[b][h * 8 + 0], st[b][h * 8 + 1]);
          u32 a1 = pk2(st[b][h * 8 + 2], st[b][h * 8 + 3]);
          u32 a2 = pk2(st[b][h * 8 + 4], st[b][h * 8 + 5]);
          u32 a3 = pk2(st[b][h * 8 + 6], st[b][h * 8 + 7]);
          pl32swap(a0, a2);  // distinct values -> distinct regs
          pl32swap(a1, a3);
          union { u32 w[4]; bf16x8 v; } pb;
          pb.w[0] = a0; pb.w[1] = a1; pb.w[2] = a2; pb.w[3] = a3;
          const int c = 2 * b + h;
          __builtin_amdgcn_s_setprio(1);
#pragma unroll
          for (int db = 0; db < 2; ++db) {
            bf16x8 vf = ldb8(&Vt[cur][db * 32 + l32][c * 16 + hi * 8]);
            oacc[db] = mfma32(vf, pb.v, oacc[db]);
          }
          __builtin_amdgcn_s_setprio(0);
        }
      }
    }
    cur ^= 1;
  }

  // ---- combine partner halves of l, normalize, store O[q][d] bf16
  const float ltot = lsum + __shfl_xor(lsum, 32);
  const float linv = 1.f / ltot;

  u16* Op = Og + ((size_t)bb * SEQ + qlane) * DM + hh * HD;
#pragma unroll
  for (int db = 0; db < 2; ++db)
#pragma unroll
    for (int r = 0; r < 16; r += 2) {
      const int d = db * 32 + (r & 3) + 8 * (r >> 2) + 4 * hi;
      u32 pk = cvtpk(oacc[db][r] * linv, oacc[db][r + 1] * linv);
      *reinterpret_cast<u32*>(Op + d) = pk;
    }
}

// ---------------------------------------------------------------- launcher
extern "C" void kernel_launch(void* const* d_in, const int* in_sizes, int n_in,
                              void* d_out, int out_size, void* d_ws,
                              size_t ws_size, hipStream_t stream) {
  const float* x  = (const float*)d_in[0];
  const float* Wq = (const float*)d_in[1];
  const float* bq = (const float*)d_in[2];
  const float* Wk = (const float*)d_in[3];
  const float* bk = (const float*)d_in[4];
  const float* Wv = (const float*)d_in[5];
  const float* bv = (const float*)d_in[6];
  const float* Wo = (const float*)d_in[7];
  const float* bo = (const float*)d_in[8];
  float* out = (float*)d_out;

  u16* xb   = (u16*)d_ws;                       // [8192][768] bf16
  u16* Wall = xb + (size_t)MR * DM;             // 4 x [768][768] bf16
  u16* QKV  = Wall + (size_t)4 * DM * DM;       // Q,K: [bh][s][64]; V: [bh][d][s]
  u16* PRE  = QKV + (size_t)3 * MR * DM;        // [8192][768] bf16

  cvt_kernel<<<dim3(MR * DM / 8 / 256), 256, 0, stream>>>(x, xb, MR * DM / 8);
  cvt_w_kernel<<<dim3(DM * DM / 8 / 256, 4), 256, 0, stream>>>(Wq, Wk, Wv, Wo,
                                                               Wall);
  gemm_qkv_kernel<<<dim3(MR / 128, DM / 128, 3), 256, 0, stream>>>(
      xb, Wall, bq, bk, bv, QKV);
  attn_kernel<<<dim3(768), 256, 0, stream>>>(
      QKV, QKV + (size_t)MR * DM, QKV + (size_t)2 * MR * DM, PRE);
  gemm_out_kernel<<<dim3(MR / 128, DM / 128), 256, 0, stream>>>(
      PRE, Wall + (size_t)3 * DM * DM, bo, out);
}